// Round 13
// baseline (92.549 us; speedup 1.0000x reference)
//
#include <hip/hip_runtime.h>

typedef float f32x4 __attribute__((ext_vector_type(4)));
typedef float f32x16 __attribute__((ext_vector_type(16)));
typedef short short8 __attribute__((ext_vector_type(8)));
typedef unsigned short ushort_t;
typedef unsigned int uint_t;

// (B,T,D,H) = (64, 32, 256, 4); DIMS = [1024, 512, 256, 128, 64, 4]
constexpr int O_CAM   = 0;
constexpr int O_ROT   = 64;
constexpr int O_TRANS = 320;
constexpr int O_PLANE = 512;
constexpr int O_VALID = 66048;

// Workspace layout (byte offsets)
constexpr size_t B_G1   = 0;         // f32 [64][256]
constexpr size_t B_G2   = 65536;     // f32 [64][256]
constexpr size_t B_ACC  = 131072;    // f32 [64][8]
constexpr size_t B_ABF  = 133120;    // bf16 [4][64][32][512]  (A' = emb@W0a + G + b0)
constexpr size_t B_CBF  = 8521728;   // bf16 [4][64][32][512]
constexpr size_t B_BT1  = 16910336;  // bf16 frag [4][32ks][8nt][64][8]   (32x32x16 layout)
constexpr size_t B_BT2  = 17958912;  // bf16 frag [4][16ks][4nt][64][8]   (32x32x16 layout)
constexpr size_t B_BT3  = 18221056;  // bf16 frag [4][4][4][64][8]        (16x16x32 layout)
constexpr size_t B_BT0F = 18286592;  // bf16 frag [4h][32ks][32nt][64][8] (full W0, 16x16)
constexpr size_t B_BT4  = 22480896;  // bf16 frag [4h][2ks][64][8]  (w4, N=16 padded)
// end = 22489088 bytes (~22.5 MB)

__device__ __forceinline__ ushort_t f2bf(float f) {
    uint_t u = __float_as_uint(f);
    return (ushort_t)((u + 0x7FFFu + ((u >> 16) & 1u)) >> 16);
}

// packed f32x2 -> bf16x2 round-to-nearest-even, 1 VALU op
__device__ __forceinline__ uint_t cvt_pk_bf16(float lo, float hi) {
    uint_t r;
    asm("v_cvt_pk_bf16_f32 %0, %1, %2" : "=v"(r) : "v"(lo), "v"(hi));
    return r;
}

__device__ __forceinline__ uint_t bfadd2_relu(uint_t a, uint_t c) {
    const float lo = __uint_as_float(a << 16) + __uint_as_float(c << 16);
    const float hi = __uint_as_float(a & 0xffff0000u) + __uint_as_float(c & 0xffff0000u);
    return cvt_pk_bf16(fmaxf(lo, 0.f), fmaxf(hi, 0.f));
}

// ================= K-prepA: W0 fragments (LDS-staged, coalesced) + group means =================
__global__ __launch_bounds__(256) void k_prepA(
    const float* __restrict__ emb, const int* __restrict__ np_,
    const float* __restrict__ w0, ushort_t* __restrict__ bt0f,
    float* __restrict__ g1, float* __restrict__ g2)
{
    __shared__ float stg[4][32][18];
    const int l = threadIdx.x & 63;
    const int u = threadIdx.x >> 6;
    const int c = blockIdx.x * 4 + u;
    if (c >= 4160) return;
    if (c < 4096) {
        const int h = c >> 10, ks = (c >> 5) & 31, nt = c & 31;
        const float* src = w0 + ((size_t)h*1024 + ks*32 + (l >> 1))*512 + nt*16 + (l & 1)*8;
        const float4 v0 = *(const float4*)(src);
        const float4 v1 = *(const float4*)(src + 4);
        float* srow = &stg[u][l >> 1][(l & 1)*8];
        srow[0]=v0.x; srow[1]=v0.y; srow[2]=v0.z; srow[3]=v0.w;
        srow[4]=v1.x; srow[5]=v1.y; srow[6]=v1.z; srow[7]=v1.w;
        asm volatile("s_waitcnt lgkmcnt(0)" ::: "memory");
        const int d0 = (l >> 4) << 3, n = l & 15;
        short8 o;
        #pragma unroll
        for (int j = 0; j < 8; ++j) o[j] = (short)f2bf(stg[u][d0 + j][n]);
        *(short8*)(bt0f + (size_t)c*512 + (size_t)l*8) = o;
    } else {
        const int b = c - 4096;
        const int n0 = np_[2*b], n1 = np_[2*b+1];
        const float* e = emb + (size_t)b*8192;
        #pragma unroll
        for (int dd = 0; dd < 4; ++dd) {
            const int d = l + 64*dd;
            float a1 = 0.f, a2 = 0.f;
            for (int t = 0; t < 32; ++t) {
                float v = e[t*256 + d];
                if (t < n0) a1 += v;
                else if (t < n0 + n1) a2 += v;
            }
            g1[b*256 + d] = a1 / n0;
            g2[b*256 + d] = a2 / n1;
        }
    }
}

// ================= K-ACp: A'/C GEMMs (bf16 out, 16x16) + w1..w4 frag prep + acc zero + valid =================
// blocks [0,512): AC (b = x&63, hc = x>>6). blocks [512,867): prepB units (4/block).
__global__ __launch_bounds__(256) void k_ACp(
    const float* __restrict__ emb, const ushort_t* __restrict__ bt0f,
    const float* __restrict__ g1, const float* __restrict__ g2,
    const float* __restrict__ b0,
    ushort_t* __restrict__ Abf, ushort_t* __restrict__ Cbf,
    const float* __restrict__ w1, const float* __restrict__ w2, const float* __restrict__ w3,
    const float* __restrict__ w4,
    ushort_t* __restrict__ bt1, ushort_t* __restrict__ bt2, ushort_t* __restrict__ bt3,
    ushort_t* __restrict__ bt4,
    const int* __restrict__ np_, float* __restrict__ accz, float* __restrict__ out)
{
    __shared__ __align__(16) char es[16384];       // bf16 [32][256], stride 512B, swizzled
    __shared__ __align__(16) ushort_t gs[512];     // bf16 [g1|g2]
    __shared__ float stg[4][32][18];               // prepB staging (576 f32 per unit)

    const int tid = threadIdx.x;
    const int l = tid & 63;

    if (blockIdx.x >= 512) {
        // ---- prepB path ----
        const int u = tid >> 6;
        int c = (blockIdx.x - 512) * 4 + u;
        if (c >= 1417) return;
        float* F = &stg[u][0][0];
        if (c < 1280) {
            // w1 / w2 fragments in 32x32x16 layout: lane l holds
            // W[d = ks*16 + (l>>5)*8 + j][n = nt*32 + (l&31)]
            const float* w; ushort_t* dst; int K, N, h, ks, nt;
            if (c < 1024) {
                h = c >> 8; const int rem = c & 255; ks = rem >> 3; nt = rem & 7;
                w = w1; K = 512; N = 256; dst = bt1 + (size_t)c*512;
            } else {
                const int c2 = c - 1024;
                h = c2 >> 6; const int rem = c2 & 63; ks = rem >> 2; nt = rem & 3;
                w = w2; K = 256; N = 128; dst = bt2 + (size_t)c2*512;
            }
            // stage 16(d) x 32(n) tile, coalesced 32B/lane
            const float* src = w + ((size_t)(h*K + ks*16 + (l >> 2)))*N + nt*32 + (l & 3)*8;
            const float4 v0 = *(const float4*)(src);
            const float4 v1 = *(const float4*)(src + 4);
            float* srow = F + (l >> 2)*33 + (l & 3)*8;
            srow[0]=v0.x; srow[1]=v0.y; srow[2]=v0.z; srow[3]=v0.w;
            srow[4]=v1.x; srow[5]=v1.y; srow[6]=v1.z; srow[7]=v1.w;
            asm volatile("s_waitcnt lgkmcnt(0)" ::: "memory");
            short8 o;
            #pragma unroll
            for (int j = 0; j < 8; ++j)
                o[j] = (short)f2bf(F[((l >> 5)*8 + j)*33 + (l & 31)]);
            *(short8*)(dst + (size_t)l*8) = o;
        } else if (c < 1344) {
            // w3 fragments in 16x16x32 layout (unchanged)
            const int c3 = c - 1280;
            const int h = c3 >> 4, rem = c3 & 15, ks = rem >> 2, nt = rem & 3;
            const float* src = w3 + ((size_t)(h*128 + ks*32 + (l >> 1)))*64 + nt*16 + (l & 1)*8;
            const float4 v0 = *(const float4*)(src);
            const float4 v1 = *(const float4*)(src + 4);
            float* srow = F + (l >> 1)*18 + (l & 1)*8;
            srow[0]=v0.x; srow[1]=v0.y; srow[2]=v0.z; srow[3]=v0.w;
            srow[4]=v1.x; srow[5]=v1.y; srow[6]=v1.z; srow[7]=v1.w;
            asm volatile("s_waitcnt lgkmcnt(0)" ::: "memory");
            short8 o;
            #pragma unroll
            for (int j = 0; j < 8; ++j)
                o[j] = (short)f2bf(F[(((l >> 4) << 3) + j)*18 + (l & 15)]);
            *(short8*)(bt3 + (size_t)c3*512 + (size_t)l*8) = o;
        } else if (c == 1344) {
            #pragma unroll
            for (int i = 0; i < 8; ++i) accz[l*8 + i] = 0.f;
        } else if (c < 1409) {
            const int b = c - 1345;
            const int n0 = np_[2*b], n1 = np_[2*b+1];
            float* dst = out + O_VALID + b*1024;
            #pragma unroll
            for (int i = 0; i < 16; ++i) {
                const int j = l*16 + i;
                const int t = j >> 5, s = j & 31;
                dst[j] = (t < n0 && s >= n0 && s < n0 + n1) ? 1.f : 0.f;
            }
        } else {
            // w4 fragments: N=16 (cols 0..3 real, rest zero), K=64 (2 ks), 16x16 layout
            const int uu = c - 1409;
            const int h = uu >> 1, ks = uu & 1;
            const int n = l & 15;
            const int d0 = ks*32 + ((l >> 4) << 3);
            short8 o;
            #pragma unroll
            for (int j = 0; j < 8; ++j)
                o[j] = (n < 4) ? (short)f2bf(w4[(size_t)h*256 + (d0 + j)*4 + n]) : (short)0;
            *(short8*)(bt4 + ((size_t)uu*64 + l)*8) = o;
        }
        return;
    }

    // ---- AC path (unchanged, 16x16) ----
    const int b = blockIdx.x & 63, hc = blockIdx.x >> 6;
    const int h = hc >> 1, isC = hc & 1;
    const int w4w = tid >> 6;
    const int lrow = l & 15, lko = l >> 4;

    {
        const float* eb = emb + (size_t)b*8192;
        #pragma unroll
        for (int j = 0; j < 16; ++j) {
            const int flat = j*256 + tid;
            const int row = flat >> 7, cp = flat & 127;
            const float2 v = *(const float2*)(eb + row*256 + cp*2);
            const uint_t p = (uint_t)f2bf(v.x) | ((uint_t)f2bf(v.y) << 16);
            const int byte = (row*512 + cp*4) ^ ((row & 7) << 4);
            *(uint_t*)(es + byte) = p;
        }
    }
    if (!isC && tid < 64) {
        const float* src = (tid < 32) ? (g1 + b*256 + tid*8) : (g2 + b*256 + (tid - 32)*8);
        const float4 v0 = *(const float4*)(src);
        const float4 v1 = *(const float4*)(src + 4);
        short8 o;
        o[0] = (short)f2bf(v0.x); o[1] = (short)f2bf(v0.y);
        o[2] = (short)f2bf(v0.z); o[3] = (short)f2bf(v0.w);
        o[4] = (short)f2bf(v1.x); o[5] = (short)f2bf(v1.y);
        o[6] = (short)f2bf(v1.z); o[7] = (short)f2bf(v1.w);
        *(short8*)(gs + tid*8) = o;
    }
    __syncthreads();

    f32x4 acc[2][8];
    #pragma unroll
    for (int mt = 0; mt < 2; ++mt)
        #pragma unroll
        for (int nt = 0; nt < 8; ++nt) acc[mt][nt] = (f32x4){0.f,0.f,0.f,0.f};

    const ushort_t* basef = bt0f + (size_t)h*(32*32*512) + (size_t)(w4w*8)*512 + (size_t)l*8;

    {
        const int ksE0 = isC ? 8 : 0;
        for (int kk = 0; kk < 8; ++kk) {
            short8 bfv[8];
            const ushort_t* bp = basef + (size_t)(ksE0 + kk)*16384;
            #pragma unroll
            for (int nt = 0; nt < 8; ++nt) bfv[nt] = *(const short8*)(bp + nt*512);
            const int o = (lrow*512 + kk*64 + lko*16) ^ ((lrow & 7) << 4);
            const short8 a0 = *(const short8*)(es + o);
            const short8 a1 = *(const short8*)(es + o + 8192);
            __builtin_amdgcn_s_setprio(1);
            #pragma unroll
            for (int nt = 0; nt < 8; ++nt) {
                acc[0][nt] = __builtin_amdgcn_mfma_f32_16x16x32_bf16(a0, bfv[nt], acc[0][nt], 0, 0, 0);
                acc[1][nt] = __builtin_amdgcn_mfma_f32_16x16x32_bf16(a1, bfv[nt], acc[1][nt], 0, 0, 0);
            }
            __builtin_amdgcn_s_setprio(0);
        }
    }
    if (!isC) {
        for (int kk = 0; kk < 16; ++kk) {
            short8 bfv[8];
            const ushort_t* bp = basef + (size_t)(16 + kk)*16384;
            #pragma unroll
            for (int nt = 0; nt < 8; ++nt) bfv[nt] = *(const short8*)(bp + nt*512);
            const short8 ag = *(const short8*)(gs + kk*32 + lko*8);
            __builtin_amdgcn_s_setprio(1);
            #pragma unroll
            for (int nt = 0; nt < 8; ++nt) {
                acc[0][nt] = __builtin_amdgcn_mfma_f32_16x16x32_bf16(ag, bfv[nt], acc[0][nt], 0, 0, 0);
                acc[1][nt] = __builtin_amdgcn_mfma_f32_16x16x32_bf16(ag, bfv[nt], acc[1][nt], 0, 0, 0);
            }
            __builtin_amdgcn_s_setprio(0);
        }
    }

    ushort_t* dst = (isC ? Cbf : Abf) + (size_t)(h*64 + b)*32*512;
    #pragma unroll
    for (int nt = 0; nt < 8; ++nt) {
        const int col = (w4w*8 + nt)*16 + lrow;
        const float g = isC ? 0.f : b0[h*512 + col];
        #pragma unroll
        for (int mt = 0; mt < 2; ++mt)
            #pragma unroll
            for (int r = 0; r < 4; ++r) {
                const int row = mt*16 + lko*4 + r;
                dst[row*512 + col] = f2bf(acc[mt][nt][r] + g);
            }
    }
}

// ================= K-MLP: M=64 fused MLP; layers 1-2 as 32x32x16 MFMA =================
// grid 1792: x<1024: h=3, b=x>>4, t0=(x&15)*2   (rows = 2t x 32s)
//            x>=1024: y=x-1024, h=y>>8, b=(y>>2)&63, t0=(y&3)*4 (rows = 4t x 16s window)
// LDS 64KB: X0 [64][512] bf16 @0 (swz (row&31)<<4); X1 [64][256] @0 overlay (swz (row&15)<<4);
//           X2 [64][128] @49152 (swz (row&15)<<4); X3b bf16 [64][64] @32768 (swz (row&7)<<4).
__global__ __launch_bounds__(512, 2) void k_mlp(
    const ushort_t* __restrict__ Abf, const ushort_t* __restrict__ Cbf,
    const ushort_t* __restrict__ bt1, const ushort_t* __restrict__ bt2,
    const ushort_t* __restrict__ bt3, const ushort_t* __restrict__ bt4,
    const float* __restrict__ b1, const float* __restrict__ b2, const float* __restrict__ b3,
    const float* __restrict__ b4,
    const int* __restrict__ np_, float* __restrict__ out, float* __restrict__ accbuf)
{
    const int x = blockIdx.x;
    const bool isH3 = (x < 1024);
    int h, b, t0;
    int n0 = 0, n1 = 0;
    if (isH3) {
        h = 3; b = x >> 4; t0 = (x & 15) * 2;
    } else {
        const int y = x - 1024;
        h = y >> 8; b = (y >> 2) & 63; t0 = (y & 3) * 4;
        n0 = np_[2*b]; n1 = np_[2*b+1];
        if (t0 >= n0) return;
    }

    __shared__ __align__(16) char smem[65536];
    char* X   = smem;
    char* X2  = smem + 49152;
    char* X3b = smem + 32768;

    const int tid = threadIdx.x;
    const int l = tid & 63, w = tid >> 6;
    const int lrow = l & 15, lko = l >> 4;      // 16x16 lane decomposition
    const int l31 = l & 31, lh16 = (l >> 5) * 16;  // 32x32 lane decomposition
    const size_t hb = (size_t)(h*64 + b);
    const uint4* Arows = (const uint4*)(Abf + hb*32*512);   // 64 uint4 per row
    const uint4* Crows = (const uint4*)(Cbf + hb*32*512);

    // biases folded into accumulator init
    const float bias1v = b1[h*256 + w*32 + l31];
    const float bias2v = b2[h*128 + (w & 3)*32 + l31];
    const float bias3v = b3[h*64 + (w & 3)*16 + lrow];
    const float bias4v = b4[h*4 + (lrow & 3)];

    // ---- prefetch first layer1 B-frag (independent of build) ----
    const ushort_t* bp1 = bt1 + (size_t)(h*256 + w)*512 + (size_t)l*8;   // [h][ks][nt=w]
    short8 bb[2];
    bb[0] = *(const short8*)(bp1);

    // ---- build full X0 = relu(A'[t] + C[s]) : [64][512] bf16, swz (row&31)<<4 ----
    #pragma unroll
    for (int i = 0; i < 8; ++i) {
        const int flat = i*512 + tid;        // [64 rows][64 uint4]
        const int row = flat >> 6, q4 = flat & 63;
        int trow, crow;
        if (isH3) { trow = t0 + (row >> 5); crow = row & 31; }
        else      { trow = t0 + (row >> 4); crow = n0 + (row & 15); }
        const uint4 aa = Arows[(size_t)trow*64 + q4];
        const uint4 cc = Crows[(size_t)crow*64 + q4];
        uint4 v;
        v.x = bfadd2_relu(aa.x, cc.x);
        v.y = bfadd2_relu(aa.y, cc.y);
        v.z = bfadd2_relu(aa.z, cc.z);
        v.w = bfadd2_relu(aa.w, cc.w);
        *(uint4*)(X + ((row*1024 + q4*16) ^ ((row & 31) << 4))) = v;
    }
    __syncthreads();                                           // [bar 1]

    // ---- layer1: 32x32x16, K=512 (32 ks), M=64 (2 mt), wave owns nt=w (32 cols) ----
    f32x16 acc1[2];
    #pragma unroll
    for (int i = 0; i < 16; ++i) { acc1[0][i] = bias1v; acc1[1][i] = bias1v; }

    const int xbase0 = l31*1024;          // row = l31 (mt=0); mt=1 adds 32768
    const int xrA = l31 << 4;             // (row&31)<<4 == l31<<4 for both mt
    #pragma unroll
    for (int ks = 0; ks < 32; ++ks) {
        if (ks < 31) bb[(ks+1) & 1] = *(const short8*)(bp1 + (size_t)(ks+1)*4096);
        const int off = (ks*32 + lh16) ^ xrA;
        __builtin_amdgcn_s_setprio(1);
        const short8 a0 = *(const short8*)(X + xbase0 + off);
        acc1[0] = __builtin_amdgcn_mfma_f32_32x32x16_bf16(a0, bb[ks & 1], acc1[0], 0, 0, 0);
        const short8 a1 = *(const short8*)(X + xbase0 + 32768 + off);
        acc1[1] = __builtin_amdgcn_mfma_f32_32x32x16_bf16(a1, bb[ks & 1], acc1[1], 0, 0, 0);
        __builtin_amdgcn_s_setprio(0);
    }
    __syncthreads();                                           // [bar 2] X0 reads done

    // ---- X1 write (overlays X0 @0..32K): [64][256] bf16, swz (row&15)<<4 ----
    {
        const int colX1x2 = (w*32 + l31) * 2;
        #pragma unroll
        for (int mt = 0; mt < 2; ++mt)
            #pragma unroll
            for (int r = 0; r < 16; ++r) {
                const int row = mt*32 + (r & 3) + 8*(r >> 2) + 4*(l >> 5);
                const float v = fmaxf(acc1[mt][r], 0.f);
                *(ushort_t*)(X + ((row*512 + colX1x2) ^ ((row & 15) << 4))) =
                    (ushort_t)cvt_pk_bf16(v, v);
            }
    }
    __syncthreads();                                           // [bar 3]

    // ---- layer2: 32x32x16, K=256 (16 ks); wave = (mt=w>>2, nt=w&3); X2 @49152 ----
    f32x16 acc2;
    #pragma unroll
    for (int i = 0; i < 16; ++i) acc2[i] = bias2v;
    {
        const int mt2 = w >> 2;
        const ushort_t* bp2 = bt2 + (size_t)(h*64 + (w & 3))*512 + (size_t)l*8;
        const int xbase2 = (mt2*32 + l31) * 512;
        const int xrB = lrow << 4;        // (row&15)<<4 == (l31&15)<<4
        short8 b2b[2];
        b2b[0] = *(const short8*)(bp2);
        #pragma unroll
        for (int ks = 0; ks < 16; ++ks) {
            if (ks < 15) b2b[(ks+1) & 1] = *(const short8*)(bp2 + (size_t)(ks+1)*2048);
            const int off = (ks*32 + lh16) ^ xrB;
            __builtin_amdgcn_s_setprio(1);
            const short8 a0 = *(const short8*)(X + xbase2 + off);
            acc2 = __builtin_amdgcn_mfma_f32_32x32x16_bf16(a0, b2b[ks & 1], acc2, 0, 0, 0);
            __builtin_amdgcn_s_setprio(0);
        }
    }
    {
        const int colX2x2 = ((w & 3)*32 + l31) * 2;
        const int mt2 = w >> 2;
        #pragma unroll
        for (int r = 0; r < 16; ++r) {
            const int row = mt2*32 + (r & 3) + 8*(r >> 2) + 4*(l >> 5);
            const float v = fmaxf(acc2[r], 0.f);
            *(ushort_t*)(X2 + ((row*256 + colX2x2) ^ ((row & 15) << 4))) =
                (ushort_t)cvt_pk_bf16(v, v);
        }
    }
    __syncthreads();                                           // [bar 4]

    // ---- layer3: 16x16x32, K=128; wave = (nt=w&3, mhalf=w>>2); X3b bf16 @32768 ----
    const int mhalf = w >> 2;
    f32x4 acc3[2];
    acc3[0] = (f32x4){bias3v, bias3v, bias3v, bias3v};
    acc3[1] = (f32x4){bias3v, bias3v, bias3v, bias3v};
    {
        const ushort_t* bp = bt3 + (size_t)(h*16 + (w & 3))*512 + (size_t)l*8;
        #pragma unroll
        for (int ks = 0; ks < 4; ++ks) {
            const short8 bf = *(const short8*)(bp + (size_t)ks*2048);
            __builtin_amdgcn_s_setprio(1);
            #pragma unroll
            for (int mi = 0; mi < 2; ++mi) {
                const int mt = mhalf*2 + mi;
                const int row = mt*16 + lrow;
                const short8 a0 = *(const short8*)(X2 + ((row*256 + ks*64 + lko*16) ^ ((row & 15) << 4)));
                acc3[mi] = __builtin_amdgcn_mfma_f32_16x16x32_bf16(a0, bf, acc3[mi], 0, 0, 0);
            }
            __builtin_amdgcn_s_setprio(0);
        }
    }
    {
        const int col = (w & 3)*16 + lrow;
        #pragma unroll
        for (int mi = 0; mi < 2; ++mi) {
            const int mt = mhalf*2 + mi;
            #pragma unroll
            for (int r = 0; r < 4; ++r) {
                const int row = mt*16 + lko*4 + r;
                const float v = fmaxf(acc3[mi][r], 0.f);
                *(ushort_t*)(X3b + ((row*128 + col*2) ^ ((row & 7) << 4))) =
                    (ushort_t)cvt_pk_bf16(v, v);
            }
        }
    }
    __syncthreads();                                           // [bar 5]

    // ---- layer4 via MFMA: M=64, K=64, N=16 (cols 0..3 real); waves 0..3, direct output ----
    if (w < 4) {
        const int mt = w;
        f32x4 acc4 = (f32x4){bias4v, bias4v, bias4v, bias4v};
        const ushort_t* bp = bt4 + (size_t)(h*2)*512 + (size_t)l*8;
        #pragma unroll
        for (int ks = 0; ks < 2; ++ks) {
            const short8 bf = *(const short8*)(bp + (size_t)ks*512);
            const short8 a0 = *(const short8*)(X3b + (((mt*16 + lrow)*128 + ks*64 + lko*16) ^ ((lrow & 7) << 4)));
            acc4 = __builtin_amdgcn_mfma_f32_16x16x32_bf16(a0, bf, acc4, 0, 0, 0);
        }

        if (isH3) {
            if (lrow == 0) {
                #pragma unroll
                for (int r = 0; r < 4; ++r) {
                    const int row = mt*16 + lko*4 + r;
                    out[O_PLANE + b*1024 + (t0 + (row >> 5))*32 + (row & 31)] =
                        1.f / (1.f + expf(-acc4[r]));
                }
            }
        } else {
            const int nj = (h == 0) ? 1 : ((h == 1) ? 4 : 3);
            float v = 0.f;
            #pragma unroll
            for (int r = 0; r < 4; ++r) {
                const int row = mt*16 + lko*4 + r;
                const int tq = row >> 4, sr = row & 15;
                if ((t0 + tq) < n0 && sr < n1) v += acc4[r];
            }
            v += __shfl_down(v, 32);
            v += __shfl_down(v, 16);
            if (lko == 0 && lrow < nj) {
                const int slot = (h == 0) ? 0 : ((h == 1) ? 1 + lrow : 5 + lrow);
                atomicAdd(&accbuf[b*8 + slot], v);
            }
        }
    }
}

// ================= K-final: finalize scalar reductions =================
__global__ __launch_bounds__(512) void k_final(
    const int* __restrict__ np_, const float* __restrict__ acc, float* __restrict__ out)
{
    const int tid = threadIdx.x;
    const int b = tid >> 3, sl = tid & 7;
    const int n0 = np_[2*b], n1 = np_[2*b+1];
    const float pf = (float)(n0 * n1);
    const float v = acc[b*8 + sl] / pf;
    if (sl == 0)      out[O_CAM + b] = 1.f / (1.f + expf(-v));
    else if (sl <= 4) out[O_ROT + b*4 + (sl - 1)] = v;
    else              out[O_TRANS + b*3 + (sl - 5)] = v;
}

extern "C" void kernel_launch(void* const* d_in, const int* in_sizes, int n_in,
                              void* d_out, int out_size, void* d_ws, size_t ws_size,
                              hipStream_t stream) {
    (void)in_sizes; (void)n_in; (void)out_size; (void)ws_size;
    const float* emb = (const float*)d_in[0];
    const int*   np_ = (const int*)d_in[1];
    const float* w0  = (const float*)d_in[2];
    const float* b0  = (const float*)d_in[3];
    const float* w1  = (const float*)d_in[4];
    const float* b1  = (const float*)d_in[5];
    const float* w2  = (const float*)d_in[6];
    const float* b2  = (const float*)d_in[7];
    const float* w3  = (const float*)d_in[8];
    const float* b3  = (const float*)d_in[9];
    const float* w4  = (const float*)d_in[10];
    const float* b4  = (const float*)d_in[11];

    char* W = (char*)d_ws;
    float* out = (float*)d_out;
    float*    g1   = (float*)(W + B_G1);
    float*    g2   = (float*)(W + B_G2);
    float*    acc  = (float*)(W + B_ACC);
    ushort_t* Abf  = (ushort_t*)(W + B_ABF);
    ushort_t* Cbf  = (ushort_t*)(W + B_CBF);
    ushort_t* bt1  = (ushort_t*)(W + B_BT1);
    ushort_t* bt2  = (ushort_t*)(W + B_BT2);
    ushort_t* bt3  = (ushort_t*)(W + B_BT3);
    ushort_t* bt0f = (ushort_t*)(W + B_BT0F);
    ushort_t* bt4  = (ushort_t*)(W + B_BT4);

    k_prepA<<<1040, 256, 0, stream>>>(emb, np_, w0, bt0f, g1, g2);
    k_ACp<<<867, 256, 0, stream>>>(emb, bt0f, g1, g2, b0, Abf, Cbf,
                                   w1, w2, w3, w4, bt1, bt2, bt3, bt4, np_, acc, out);
    k_mlp<<<1792, 512, 0, stream>>>(Abf, Cbf, bt1, bt2, bt3, bt4,
                                    b1, b2, b3, b4, np_, out, acc);
    k_final<<<1, 512, 0, stream>>>(np_, acc, out);
}

// Round 14
// 85.949 us; speedup vs baseline: 1.0768x; 1.0768x over previous
//
#include <hip/hip_runtime.h>

typedef float f32x4 __attribute__((ext_vector_type(4)));
typedef short short8 __attribute__((ext_vector_type(8)));
typedef unsigned short ushort_t;
typedef unsigned int uint_t;

// (B,T,D,H) = (64, 32, 256, 4); DIMS = [1024, 512, 256, 128, 64, 4]
constexpr int O_CAM   = 0;
constexpr int O_ROT   = 64;
constexpr int O_TRANS = 320;
constexpr int O_PLANE = 512;
constexpr int O_VALID = 66048;

// Workspace layout (byte offsets)
constexpr size_t B_G1   = 0;         // f32 [64][256]
constexpr size_t B_G2   = 65536;     // f32 [64][256]
constexpr size_t B_ACC  = 131072;    // f32 [64][8]
constexpr size_t B_ABF  = 133120;    // bf16 [4][64][32][512]  (A' = emb@W0a + G + b0)
constexpr size_t B_CBF  = 8521728;   // bf16 [4][64][32][512]
constexpr size_t B_BT1  = 16910336;  // bf16 frag [4][16ks][16nt][64][8]
constexpr size_t B_BT2  = 17958912;  // bf16 frag [4][8][8][64][8]
constexpr size_t B_BT3  = 18221056;  // bf16 frag [4][4][4][64][8]
constexpr size_t B_BT0F = 18286592;  // bf16 frag [4h][32ks][32nt][64][8]  (full W0)
constexpr size_t B_BT4  = 22480896;  // bf16 frag [4h][2ks][64][8]  (w4, N=16 padded)
// end = 22489088 bytes (~22.5 MB)

__device__ __forceinline__ ushort_t f2bf(float f) {
    uint_t u = __float_as_uint(f);
    return (ushort_t)((u + 0x7FFFu + ((u >> 16) & 1u)) >> 16);
}

// packed f32x2 -> bf16x2 round-to-nearest-even, 1 VALU op
__device__ __forceinline__ uint_t cvt_pk_bf16(float lo, float hi) {
    uint_t r;
    asm("v_cvt_pk_bf16_f32 %0, %1, %2" : "=v"(r) : "v"(lo), "v"(hi));
    return r;
}

__device__ __forceinline__ uint_t bfadd2_relu(uint_t a, uint_t c) {
    const float lo = __uint_as_float(a << 16) + __uint_as_float(c << 16);
    const float hi = __uint_as_float(a & 0xffff0000u) + __uint_as_float(c & 0xffff0000u);
    return cvt_pk_bf16(fmaxf(lo, 0.f), fmaxf(hi, 0.f));
}

// ================= K-prepA: W0 fragments (LDS-staged, coalesced) + group means =================
__global__ __launch_bounds__(256) void k_prepA(
    const float* __restrict__ emb, const int* __restrict__ np_,
    const float* __restrict__ w0, ushort_t* __restrict__ bt0f,
    float* __restrict__ g1, float* __restrict__ g2)
{
    __shared__ float stg[4][32][18];
    const int l = threadIdx.x & 63;
    const int u = threadIdx.x >> 6;
    const int c = blockIdx.x * 4 + u;
    if (c >= 4160) return;
    if (c < 4096) {
        const int h = c >> 10, ks = (c >> 5) & 31, nt = c & 31;
        const float* src = w0 + ((size_t)h*1024 + ks*32 + (l >> 1))*512 + nt*16 + (l & 1)*8;
        const float4 v0 = *(const float4*)(src);
        const float4 v1 = *(const float4*)(src + 4);
        float* srow = &stg[u][l >> 1][(l & 1)*8];
        srow[0]=v0.x; srow[1]=v0.y; srow[2]=v0.z; srow[3]=v0.w;
        srow[4]=v1.x; srow[5]=v1.y; srow[6]=v1.z; srow[7]=v1.w;
        asm volatile("s_waitcnt lgkmcnt(0)" ::: "memory");
        const int d0 = (l >> 4) << 3, n = l & 15;
        short8 o;
        #pragma unroll
        for (int j = 0; j < 8; ++j) o[j] = (short)f2bf(stg[u][d0 + j][n]);
        *(short8*)(bt0f + (size_t)c*512 + (size_t)l*8) = o;
    } else {
        const int b = c - 4096;
        const int n0 = np_[2*b], n1 = np_[2*b+1];
        const float* e = emb + (size_t)b*8192;
        #pragma unroll
        for (int dd = 0; dd < 4; ++dd) {
            const int d = l + 64*dd;
            float a1 = 0.f, a2 = 0.f;
            for (int t = 0; t < 32; ++t) {
                float v = e[t*256 + d];
                if (t < n0) a1 += v;
                else if (t < n0 + n1) a2 += v;
            }
            g1[b*256 + d] = a1 / n0;
            g2[b*256 + d] = a2 / n1;
        }
    }
}

// ================= K-ACp: A'/C GEMMs (bf16 out) + absorbed w1..w4 frag prep + acc zero + valid =================
// blocks [0,512): AC (b = x&63, hc = x>>6). blocks [512,867): prepB units (4/block).
__global__ __launch_bounds__(256) void k_ACp(
    const float* __restrict__ emb, const ushort_t* __restrict__ bt0f,
    const float* __restrict__ g1, const float* __restrict__ g2,
    const float* __restrict__ b0,
    ushort_t* __restrict__ Abf, ushort_t* __restrict__ Cbf,
    const float* __restrict__ w1, const float* __restrict__ w2, const float* __restrict__ w3,
    const float* __restrict__ w4,
    ushort_t* __restrict__ bt1, ushort_t* __restrict__ bt2, ushort_t* __restrict__ bt3,
    ushort_t* __restrict__ bt4,
    const int* __restrict__ np_, float* __restrict__ accz, float* __restrict__ out)
{
    __shared__ __align__(16) char es[16384];       // bf16 [32][256], stride 512B, swizzled
    __shared__ __align__(16) ushort_t gs[512];     // bf16 [g1|g2]
    __shared__ float stg[4][32][18];               // prepB staging

    const int tid = threadIdx.x;
    const int l = tid & 63;

    if (blockIdx.x >= 512) {
        // ---- prepB path ----
        const int u = tid >> 6;
        int c = (blockIdx.x - 512) * 4 + u;
        if (c >= 1417) return;
        if (c < 1344) {
            const float* w; ushort_t* dst; int K, N;
            if (c < 1024)      {           w = w1; dst = bt1 + (size_t)c*512; K = 512; N = 256; }
            else if (c < 1280) { c -= 1024; w = w2; dst = bt2 + (size_t)c*512; K = 256; N = 128; }
            else               { c -= 1280; w = w3; dst = bt3 + (size_t)c*512; K = 128; N = 64;  }
            const int NT = N/16, KS_NT = (K/32)*NT;
            const int h = c / KS_NT, rem = c % KS_NT, ks = rem / NT, nt = rem % NT;
            // stage 32 rows x 16 cols, coalesced
            const float* src = w + ((size_t)(h*K + ks*32 + (l >> 1)))*N + nt*16 + (l & 1)*8;
            const float4 v0 = *(const float4*)(src);
            const float4 v1 = *(const float4*)(src + 4);
            float* srow = &stg[u][l >> 1][(l & 1)*8];
            srow[0]=v0.x; srow[1]=v0.y; srow[2]=v0.z; srow[3]=v0.w;
            srow[4]=v1.x; srow[5]=v1.y; srow[6]=v1.z; srow[7]=v1.w;
            asm volatile("s_waitcnt lgkmcnt(0)" ::: "memory");
            const int d0 = (l >> 4) << 3, n = l & 15;
            short8 o;
            #pragma unroll
            for (int j = 0; j < 8; ++j) o[j] = (short)f2bf(stg[u][d0 + j][n]);
            *(short8*)(dst + (size_t)l*8) = o;
        } else if (c == 1344) {
            #pragma unroll
            for (int i = 0; i < 8; ++i) accz[l*8 + i] = 0.f;
        } else if (c < 1409) {
            const int b = c - 1345;
            const int n0 = np_[2*b], n1 = np_[2*b+1];
            float* dst = out + O_VALID + b*1024;
            #pragma unroll
            for (int i = 0; i < 16; ++i) {
                const int j = l*16 + i;
                const int t = j >> 5, s = j & 31;
                dst[j] = (t < n0 && s >= n0 && s < n0 + n1) ? 1.f : 0.f;
            }
        } else {
            // w4 fragments: N=16 (cols 0..3 real, rest zero), K=64 (2 ks)
            const int uu = c - 1409;
            const int h = uu >> 1, ks = uu & 1;
            const int n = l & 15;
            const int d0 = ks*32 + ((l >> 4) << 3);
            short8 o;
            #pragma unroll
            for (int j = 0; j < 8; ++j)
                o[j] = (n < 4) ? (short)f2bf(w4[(size_t)h*256 + (d0 + j)*4 + n]) : (short)0;
            *(short8*)(bt4 + ((size_t)uu*64 + l)*8) = o;
        }
        return;
    }

    // ---- AC path ----
    const int b = blockIdx.x & 63, hc = blockIdx.x >> 6;
    const int h = hc >> 1, isC = hc & 1;
    const int w4w = tid >> 6;
    const int lrow = l & 15, lko = l >> 4;

    {
        const float* eb = emb + (size_t)b*8192;
        #pragma unroll
        for (int j = 0; j < 16; ++j) {
            const int flat = j*256 + tid;
            const int row = flat >> 7, cp = flat & 127;
            const float2 v = *(const float2*)(eb + row*256 + cp*2);
            const uint_t p = (uint_t)f2bf(v.x) | ((uint_t)f2bf(v.y) << 16);
            const int byte = (row*512 + cp*4) ^ ((row & 7) << 4);
            *(uint_t*)(es + byte) = p;
        }
    }
    if (!isC && tid < 64) {
        const float* src = (tid < 32) ? (g1 + b*256 + tid*8) : (g2 + b*256 + (tid - 32)*8);
        const float4 v0 = *(const float4*)(src);
        const float4 v1 = *(const float4*)(src + 4);
        short8 o;
        o[0] = (short)f2bf(v0.x); o[1] = (short)f2bf(v0.y);
        o[2] = (short)f2bf(v0.z); o[3] = (short)f2bf(v0.w);
        o[4] = (short)f2bf(v1.x); o[5] = (short)f2bf(v1.y);
        o[6] = (short)f2bf(v1.z); o[7] = (short)f2bf(v1.w);
        *(short8*)(gs + tid*8) = o;
    }
    __syncthreads();

    f32x4 acc[2][8];
    #pragma unroll
    for (int mt = 0; mt < 2; ++mt)
        #pragma unroll
        for (int nt = 0; nt < 8; ++nt) acc[mt][nt] = (f32x4){0.f,0.f,0.f,0.f};

    const ushort_t* basef = bt0f + (size_t)h*(32*32*512) + (size_t)(w4w*8)*512 + (size_t)l*8;

    // emb K-steps: A -> W0 rows [0,256) (ks 0..7); C -> rows [256,512) (ks 8..15)
    {
        const int ksE0 = isC ? 8 : 0;
        for (int kk = 0; kk < 8; ++kk) {
            short8 bfv[8];
            const ushort_t* bp = basef + (size_t)(ksE0 + kk)*16384;
            #pragma unroll
            for (int nt = 0; nt < 8; ++nt) bfv[nt] = *(const short8*)(bp + nt*512);
            const int o = (lrow*512 + kk*64 + lko*16) ^ ((lrow & 7) << 4);
            const short8 a0 = *(const short8*)(es + o);
            const short8 a1 = *(const short8*)(es + o + 8192);
            __builtin_amdgcn_s_setprio(1);
            #pragma unroll
            for (int nt = 0; nt < 8; ++nt) {
                acc[0][nt] = __builtin_amdgcn_mfma_f32_16x16x32_bf16(a0, bfv[nt], acc[0][nt], 0, 0, 0);
                acc[1][nt] = __builtin_amdgcn_mfma_f32_16x16x32_bf16(a1, bfv[nt], acc[1][nt], 0, 0, 0);
            }
            __builtin_amdgcn_s_setprio(0);
        }
    }
    // g K-steps (A only): rows [512,1024) (ks 16..31); A-fragment row-uniform
    if (!isC) {
        for (int kk = 0; kk < 16; ++kk) {
            short8 bfv[8];
            const ushort_t* bp = basef + (size_t)(16 + kk)*16384;
            #pragma unroll
            for (int nt = 0; nt < 8; ++nt) bfv[nt] = *(const short8*)(bp + nt*512);
            const short8 ag = *(const short8*)(gs + kk*32 + lko*8);
            __builtin_amdgcn_s_setprio(1);
            #pragma unroll
            for (int nt = 0; nt < 8; ++nt) {
                acc[0][nt] = __builtin_amdgcn_mfma_f32_16x16x32_bf16(ag, bfv[nt], acc[0][nt], 0, 0, 0);
                acc[1][nt] = __builtin_amdgcn_mfma_f32_16x16x32_bf16(ag, bfv[nt], acc[1][nt], 0, 0, 0);
            }
            __builtin_amdgcn_s_setprio(0);
        }
    }

    ushort_t* dst = (isC ? Cbf : Abf) + (size_t)(h*64 + b)*32*512;
    #pragma unroll
    for (int nt = 0; nt < 8; ++nt) {
        const int col = (w4w*8 + nt)*16 + lrow;
        const float g = isC ? 0.f : b0[h*512 + col];
        #pragma unroll
        for (int mt = 0; mt < 2; ++mt)
            #pragma unroll
            for (int r = 0; r < 4; ++r) {
                const int row = mt*16 + lko*4 + r;
                dst[row*512 + col] = f2bf(acc[mt][nt][r] + g);
            }
    }
}

// ================= K-MLP: M=64 fused MLP, 8 waves, 64KB LDS, MFMA layer4, bias-in-acc =================
// logical id x (after XCD swizzle): x<1024: h=3, b=x>>4, t0=(x&15)*2   (rows = 2t x 32s)
//            x>=1024: y=x-1024, h=y>>8, b=(y>>2)&63, t0=(y&3)*4 (rows = 4t x 16s window)
// LDS 64KB: X0 [64][512] bf16 @0; X1 [64][256] @0 overlay; X2 [64][128] @49152;
//           X3b bf16 [64][64] @32768.
__global__ __launch_bounds__(512, 2) void k_mlp(
    const ushort_t* __restrict__ Abf, const ushort_t* __restrict__ Cbf,
    const ushort_t* __restrict__ bt1, const ushort_t* __restrict__ bt2,
    const ushort_t* __restrict__ bt3, const ushort_t* __restrict__ bt4,
    const float* __restrict__ b1, const float* __restrict__ b2, const float* __restrict__ b3,
    const float* __restrict__ b4,
    const int* __restrict__ np_, float* __restrict__ out, float* __restrict__ accbuf)
{
    // T1 XCD-aware swizzle: grid 1792 = 8 * 224 (bijective). Blocks sharing one (h,b)
    // A'/C panel become contiguous on one XCD's L2.
    const int bid = blockIdx.x;
    const int x = (bid & 7) * 224 + (bid >> 3);
    const bool isH3 = (x < 1024);
    int h, b, t0;
    int n0 = 0, n1 = 0;
    if (isH3) {
        h = 3; b = x >> 4; t0 = (x & 15) * 2;
    } else {
        const int y = x - 1024;
        h = y >> 8; b = (y >> 2) & 63; t0 = (y & 3) * 4;
        n0 = np_[2*b]; n1 = np_[2*b+1];
        if (t0 >= n0) return;
    }

    __shared__ __align__(16) char smem[65536];
    char* X   = smem;
    char* X2  = smem + 49152;
    char* X3b = smem + 32768;

    const int tid = threadIdx.x;
    const int l = tid & 63, w = tid >> 6;
    const int lrow = l & 15, lko = l >> 4;
    const size_t hb = (size_t)(h*64 + b);
    const uint4* Arows = (const uint4*)(Abf + hb*32*512);   // 64 uint4 per row
    const uint4* Crows = (const uint4*)(Cbf + hb*32*512);

    // biases (each acc column's bias folded into accumulator init)
    const float bias1_0 = b1[h*256 + (w*2 + 0)*16 + lrow];
    const float bias1_1 = b1[h*256 + (w*2 + 1)*16 + lrow];
    const float bias2v  = b2[h*128 + w*16 + lrow];
    const float bias3v  = b3[h*64 + (w & 3)*16 + lrow];
    const float bias4v  = b4[h*4 + (lrow & 3)];

    // ---- prefetch first layer1 B-frags (independent of build) ----
    const ushort_t* bp1 = bt1 + (size_t)(h*256 + w*2)*512 + (size_t)l*8;
    short8 bb[2][2];
    bb[0][0] = *(const short8*)(bp1);
    bb[0][1] = *(const short8*)(bp1 + 512);

    // ---- build full X0 = relu(A'[t] + C[s]) : [64][512] bf16, stride 1024B, swizzled ----
    #pragma unroll
    for (int i = 0; i < 8; ++i) {
        const int flat = i*512 + tid;        // [64 rows][64 uint4]
        const int row = flat >> 6, q4 = flat & 63;
        int trow, crow;
        if (isH3) { trow = t0 + (row >> 5); crow = row & 31; }
        else      { trow = t0 + (row >> 4); crow = n0 + (row & 15); }
        const uint4 aa = Arows[(size_t)trow*64 + q4];
        const uint4 cc = Crows[(size_t)crow*64 + q4];
        uint4 v;
        v.x = bfadd2_relu(aa.x, cc.x);
        v.y = bfadd2_relu(aa.y, cc.y);
        v.z = bfadd2_relu(aa.z, cc.z);
        v.w = bfadd2_relu(aa.w, cc.w);
        *(uint4*)(X + ((row*1024 + q4*16) ^ ((row & 7) << 4))) = v;
    }
    __syncthreads();                                           // [bar 1]

    // ---- layer1: K=512 (16 ks), M=64, N=256; wave owns 2 nt; acc init = bias ----
    f32x4 acc1[4][2];
    #pragma unroll
    for (int mt = 0; mt < 4; ++mt) {
        acc1[mt][0] = (f32x4){bias1_0, bias1_0, bias1_0, bias1_0};
        acc1[mt][1] = (f32x4){bias1_1, bias1_1, bias1_1, bias1_1};
    }

    #pragma unroll
    for (int ks = 0; ks < 16; ++ks) {
        if (ks < 15) {
            bb[(ks+1)&1][0] = *(const short8*)(bp1 + (size_t)(ks+1)*8192);
            bb[(ks+1)&1][1] = *(const short8*)(bp1 + (size_t)(ks+1)*8192 + 512);
        }
        const short8 bf0 = bb[ks&1][0];
        const short8 bf1 = bb[ks&1][1];
        __builtin_amdgcn_s_setprio(1);
        #pragma unroll
        for (int mt = 0; mt < 4; ++mt) {
            const short8 a0 = *(const short8*)(X + (((mt*16 + lrow)*1024 + ks*64 + lko*16) ^ ((lrow & 7) << 4)));
            acc1[mt][0] = __builtin_amdgcn_mfma_f32_16x16x32_bf16(a0, bf0, acc1[mt][0], 0, 0, 0);
            acc1[mt][1] = __builtin_amdgcn_mfma_f32_16x16x32_bf16(a0, bf1, acc1[mt][1], 0, 0, 0);
        }
        __builtin_amdgcn_s_setprio(0);
    }
    __syncthreads();                                           // [bar 2] X0 reads done

    // ---- X1 write (overlays X0 @0..32K): [64][256] bf16 stride 512B ----
    #pragma unroll
    for (int nt = 0; nt < 2; ++nt) {
        const int col = (w*2 + nt)*16 + lrow;
        #pragma unroll
        for (int mt = 0; mt < 4; ++mt)
            #pragma unroll
            for (int r = 0; r < 4; ++r) {
                const int row = mt*16 + lko*4 + r;
                const float v = fmaxf(acc1[mt][nt][r], 0.f);
                *(ushort_t*)(X + ((row*512 + col*2) ^ ((row & 7) << 4))) =
                    (ushort_t)cvt_pk_bf16(v, v);
            }
    }
    __syncthreads();                                           // [bar 3]

    // ---- layer2: K=256, N=128; wave owns nt = w; X2 write @49152 (disjoint, no bar) ----
    f32x4 acc2[4];
    #pragma unroll
    for (int mt = 0; mt < 4; ++mt) acc2[mt] = (f32x4){bias2v, bias2v, bias2v, bias2v};
    {
        const ushort_t* bp = bt2 + (size_t)(h*64 + w)*512 + (size_t)l*8;
        short8 b2b[2];
        b2b[0] = *(const short8*)(bp);
        #pragma unroll
        for (int ks = 0; ks < 8; ++ks) {
            if (ks < 7) b2b[(ks+1)&1] = *(const short8*)(bp + (size_t)(ks+1)*4096);
            __builtin_amdgcn_s_setprio(1);
            #pragma unroll
            for (int mt = 0; mt < 4; ++mt) {
                const short8 a0 = *(const short8*)(X + (((mt*16 + lrow)*512 + ks*64 + lko*16) ^ ((lrow & 7) << 4)));
                acc2[mt] = __builtin_amdgcn_mfma_f32_16x16x32_bf16(a0, b2b[ks&1], acc2[mt], 0, 0, 0);
            }
            __builtin_amdgcn_s_setprio(0);
        }
    }
    {
        const int col = w*16 + lrow;
        #pragma unroll
        for (int mt = 0; mt < 4; ++mt)
            #pragma unroll
            for (int r = 0; r < 4; ++r) {
                const int row = mt*16 + lko*4 + r;
                const float v = fmaxf(acc2[mt][r], 0.f);
                *(ushort_t*)(X2 + ((row*256 + col*2) ^ ((row & 7) << 4))) =
                    (ushort_t)cvt_pk_bf16(v, v);
            }
    }
    __syncthreads();                                           // [bar 4]

    // ---- layer3: K=128, N=64; wave = (nt=w&3, mhalf=w>>2); X3b bf16 @32768 (disjoint) ----
    const int mhalf = w >> 2;
    f32x4 acc3[2];
    acc3[0] = (f32x4){bias3v, bias3v, bias3v, bias3v};
    acc3[1] = (f32x4){bias3v, bias3v, bias3v, bias3v};
    {
        const ushort_t* bp = bt3 + (size_t)(h*16 + (w & 3))*512 + (size_t)l*8;
        #pragma unroll
        for (int ks = 0; ks < 4; ++ks) {
            const short8 bf = *(const short8*)(bp + (size_t)ks*2048);
            __builtin_amdgcn_s_setprio(1);
            #pragma unroll
            for (int mi = 0; mi < 2; ++mi) {
                const int mt = mhalf*2 + mi;
                const short8 a0 = *(const short8*)(X2 + (((mt*16 + lrow)*256 + ks*64 + lko*16) ^ ((lrow & 7) << 4)));
                acc3[mi] = __builtin_amdgcn_mfma_f32_16x16x32_bf16(a0, bf, acc3[mi], 0, 0, 0);
            }
            __builtin_amdgcn_s_setprio(0);
        }
    }
    {
        const int col = (w & 3)*16 + lrow;
        #pragma unroll
        for (int mi = 0; mi < 2; ++mi) {
            const int mt = mhalf*2 + mi;
            #pragma unroll
            for (int r = 0; r < 4; ++r) {
                const int row = mt*16 + lko*4 + r;
                const float v = fmaxf(acc3[mi][r], 0.f);
                *(ushort_t*)(X3b + ((row*128 + col*2) ^ ((row & 7) << 4))) =
                    (ushort_t)cvt_pk_bf16(v, v);
            }
        }
    }
    __syncthreads();                                           // [bar 5]

    // ---- layer4 via MFMA: M=64, K=64, N=16 (cols 0..3 real); waves 0..3, direct output ----
    if (w < 4) {
        const int mt = w;
        f32x4 acc4 = (f32x4){bias4v, bias4v, bias4v, bias4v};
        const ushort_t* bp = bt4 + (size_t)(h*2)*512 + (size_t)l*8;
        #pragma unroll
        for (int ks = 0; ks < 2; ++ks) {
            const short8 bf = *(const short8*)(bp + (size_t)ks*512);
            const short8 a0 = *(const short8*)(X3b + (((mt*16 + lrow)*128 + ks*64 + lko*16) ^ ((lrow & 7) << 4)));
            acc4 = __builtin_amdgcn_mfma_f32_16x16x32_bf16(a0, bf, acc4, 0, 0, 0);
        }

        if (isH3) {
            if (lrow == 0) {
                #pragma unroll
                for (int r = 0; r < 4; ++r) {
                    const int row = mt*16 + lko*4 + r;
                    out[O_PLANE + b*1024 + (t0 + (row >> 5))*32 + (row & 31)] =
                        1.f / (1.f + expf(-acc4[r]));
                }
            }
        } else {
            const int nj = (h == 0) ? 1 : ((h == 1) ? 4 : 3);
            float v = 0.f;
            #pragma unroll
            for (int r = 0; r < 4; ++r) {
                const int row = mt*16 + lko*4 + r;
                const int tq = row >> 4, sr = row & 15;
                if ((t0 + tq) < n0 && sr < n1) v += acc4[r];
            }
            v += __shfl_down(v, 32);
            v += __shfl_down(v, 16);
            if (lko == 0 && lrow < nj) {
                const int slot = (h == 0) ? 0 : ((h == 1) ? 1 + lrow : 5 + lrow);
                atomicAdd(&accbuf[b*8 + slot], v);
            }
        }
    }
}

// ================= K-final: finalize scalar reductions =================
__global__ __launch_bounds__(512) void k_final(
    const int* __restrict__ np_, const float* __restrict__ acc, float* __restrict__ out)
{
    const int tid = threadIdx.x;
    const int b = tid >> 3, sl = tid & 7;
    const int n0 = np_[2*b], n1 = np_[2*b+1];
    const float pf = (float)(n0 * n1);
    const float v = acc[b*8 + sl] / pf;
    if (sl == 0)      out[O_CAM + b] = 1.f / (1.f + expf(-v));
    else if (sl <= 4) out[O_ROT + b*4 + (sl - 1)] = v;
    else              out[O_TRANS + b*3 + (sl - 5)] = v;
}

extern "C" void kernel_launch(void* const* d_in, const int* in_sizes, int n_in,
                              void* d_out, int out_size, void* d_ws, size_t ws_size,
                              hipStream_t stream) {
    (void)in_sizes; (void)n_in; (void)out_size; (void)ws_size;
    const float* emb = (const float*)d_in[0];
    const int*   np_ = (const int*)d_in[1];
    const float* w0  = (const float*)d_in[2];
    const float* b0  = (const float*)d_in[3];
    const float* w1  = (const float*)d_in[4];
    const float* b1  = (const float*)d_in[5];
    const float* w2  = (const float*)d_in[6];
    const float* b2  = (const float*)d_in[7];
    const float* w3  = (const float*)d_in[8];
    const float* b3  = (const float*)d_in[9];
    const float* w4  = (const float*)d_in[10];
    const float* b4  = (const float*)d_in[11];

    char* W = (char*)d_ws;
    float* out = (float*)d_out;
    float*    g1   = (float*)(W + B_G1);
    float*    g2   = (float*)(W + B_G2);
    float*    acc  = (float*)(W + B_ACC);
    ushort_t* Abf  = (ushort_t*)(W + B_ABF);
    ushort_t* Cbf  = (ushort_t*)(W + B_CBF);
    ushort_t* bt1  = (ushort_t*)(W + B_BT1);
    ushort_t* bt2  = (ushort_t*)(W + B_BT2);
    ushort_t* bt3  = (ushort_t*)(W + B_BT3);
    ushort_t* bt0f = (ushort_t*)(W + B_BT0F);
    ushort_t* bt4  = (ushort_t*)(W + B_BT4);

    k_prepA<<<1040, 256, 0, stream>>>(emb, np_, w0, bt0f, g1, g2);
    k_ACp<<<867, 256, 0, stream>>>(emb, bt0f, g1, g2, b0, Abf, Cbf,
                                   w1, w2, w3, w4, bt1, bt2, bt3, bt4, np_, acc, out);
    k_mlp<<<1792, 512, 0, stream>>>(Abf, Cbf, bt1, bt2, bt3, bt4,
                                    b1, b2, b3, b4, np_, out, acc);
    k_final<<<1, 512, 0, stream>>>(np_, acc, out);
}

// Round 15
// 85.747 us; speedup vs baseline: 1.0793x; 1.0024x over previous
//
#include <hip/hip_runtime.h>

typedef float f32x4 __attribute__((ext_vector_type(4)));
typedef _Float16 half8 __attribute__((ext_vector_type(8)));
typedef unsigned short ushort_t;
typedef unsigned int uint_t;

// (B,T,D,H) = (64, 32, 256, 4); DIMS = [1024, 512, 256, 128, 64, 4]
constexpr int O_CAM   = 0;
constexpr int O_ROT   = 64;
constexpr int O_TRANS = 320;
constexpr int O_PLANE = 512;
constexpr int O_VALID = 66048;

// Workspace layout (byte offsets)
constexpr size_t B_G1   = 0;         // f32 [64][256]
constexpr size_t B_G2   = 65536;     // f32 [64][256]
constexpr size_t B_ACC  = 131072;    // f32 [64][8]
constexpr size_t B_ABF  = 133120;    // f16 [4][64][32][512]  (A' = emb@W0a + G + b0)
constexpr size_t B_CBF  = 8521728;   // f16 [4][64][32][512]
constexpr size_t B_BT1  = 16910336;  // f16 frag [4][16ks][16nt][64][8]
constexpr size_t B_BT2  = 17958912;  // f16 frag [4][8][8][64][8]
constexpr size_t B_BT3  = 18221056;  // f16 frag [4][4][4][64][8]
constexpr size_t B_BT0F = 18286592;  // f16 frag [4h][32ks][32nt][64][8]  (full W0)
constexpr size_t B_BT4  = 22480896;  // f16 frag [4h][2ks][64][8]  (w4, N=16 padded)
// end = 22489088 bytes (~22.5 MB)

// f32 -> f16 bits, RNE
__device__ __forceinline__ ushort_t f2h_s(float f) {
    union { _Float16 h; ushort_t u; } cvt;
    cvt.h = (_Float16)f;
    return cvt.u;
}

// packed f32x2 -> f16x2 (RTZ), 1 VALU op
__device__ __forceinline__ uint_t cvt_pk_f16(float lo, float hi) {
    uint_t r;
    asm("v_cvt_pkrtz_f16_f32 %0, %1, %2" : "=v"(r) : "v"(lo), "v"(hi));
    return r;
}

// packed fp16: relu(a + c) in 2 VALU ops
__device__ __forceinline__ uint_t hadd2_relu(uint_t a, uint_t c) {
    uint_t r;
    asm("v_pk_add_f16 %0, %1, %2\n\tv_pk_max_f16 %0, %0, 0"
        : "=&v"(r) : "v"(a), "v"(c));
    return r;
}

// ================= K-prepA: W0 fragments (LDS-staged, coalesced) + group means =================
__global__ __launch_bounds__(256) void k_prepA(
    const float* __restrict__ emb, const int* __restrict__ np_,
    const float* __restrict__ w0, ushort_t* __restrict__ bt0f,
    float* __restrict__ g1, float* __restrict__ g2)
{
    __shared__ float stg[4][32][18];
    const int l = threadIdx.x & 63;
    const int u = threadIdx.x >> 6;
    const int c = blockIdx.x * 4 + u;
    if (c >= 4160) return;
    if (c < 4096) {
        const int h = c >> 10, ks = (c >> 5) & 31, nt = c & 31;
        const float* src = w0 + ((size_t)h*1024 + ks*32 + (l >> 1))*512 + nt*16 + (l & 1)*8;
        const float4 v0 = *(const float4*)(src);
        const float4 v1 = *(const float4*)(src + 4);
        float* srow = &stg[u][l >> 1][(l & 1)*8];
        srow[0]=v0.x; srow[1]=v0.y; srow[2]=v0.z; srow[3]=v0.w;
        srow[4]=v1.x; srow[5]=v1.y; srow[6]=v1.z; srow[7]=v1.w;
        asm volatile("s_waitcnt lgkmcnt(0)" ::: "memory");
        const int d0 = (l >> 4) << 3, n = l & 15;
        ushort_t o[8];
        #pragma unroll
        for (int j = 0; j < 8; ++j) o[j] = f2h_s(stg[u][d0 + j][n]);
        *(uint4*)(bt0f + (size_t)c*512 + (size_t)l*8) = *(uint4*)o;
    } else {
        const int b = c - 4096;
        const int n0 = np_[2*b], n1 = np_[2*b+1];
        const float* e = emb + (size_t)b*8192;
        #pragma unroll
        for (int dd = 0; dd < 4; ++dd) {
            const int d = l + 64*dd;
            float a1 = 0.f, a2 = 0.f;
            for (int t = 0; t < 32; ++t) {
                float v = e[t*256 + d];
                if (t < n0) a1 += v;
                else if (t < n0 + n1) a2 += v;
            }
            g1[b*256 + d] = a1 / n0;
            g2[b*256 + d] = a2 / n1;
        }
    }
}

// ================= K-ACp: A'/C GEMMs (f16 out) + absorbed w1..w4 frag prep + acc zero + valid =================
// blocks [0,512): AC (b = x&63, hc = x>>6). blocks [512,867): prepB units (4/block).
__global__ __launch_bounds__(256) void k_ACp(
    const float* __restrict__ emb, const ushort_t* __restrict__ bt0f,
    const float* __restrict__ g1, const float* __restrict__ g2,
    const float* __restrict__ b0,
    ushort_t* __restrict__ Abf, ushort_t* __restrict__ Cbf,
    const float* __restrict__ w1, const float* __restrict__ w2, const float* __restrict__ w3,
    const float* __restrict__ w4,
    ushort_t* __restrict__ bt1, ushort_t* __restrict__ bt2, ushort_t* __restrict__ bt3,
    ushort_t* __restrict__ bt4,
    const int* __restrict__ np_, float* __restrict__ accz, float* __restrict__ out)
{
    __shared__ __align__(16) char es[16384];       // f16 [32][256], stride 512B, swizzled
    __shared__ __align__(16) ushort_t gs[512];     // f16 [g1|g2]
    __shared__ float stg[4][32][18];               // prepB staging

    const int tid = threadIdx.x;
    const int l = tid & 63;

    if (blockIdx.x >= 512) {
        // ---- prepB path ----
        const int u = tid >> 6;
        int c = (blockIdx.x - 512) * 4 + u;
        if (c >= 1417) return;
        if (c < 1344) {
            const float* w; ushort_t* dst; int K, N;
            if (c < 1024)      {           w = w1; dst = bt1 + (size_t)c*512; K = 512; N = 256; }
            else if (c < 1280) { c -= 1024; w = w2; dst = bt2 + (size_t)c*512; K = 256; N = 128; }
            else               { c -= 1280; w = w3; dst = bt3 + (size_t)c*512; K = 128; N = 64;  }
            const int NT = N/16, KS_NT = (K/32)*NT;
            const int h = c / KS_NT, rem = c % KS_NT, ks = rem / NT, nt = rem % NT;
            // stage 32 rows x 16 cols, coalesced
            const float* src = w + ((size_t)(h*K + ks*32 + (l >> 1)))*N + nt*16 + (l & 1)*8;
            const float4 v0 = *(const float4*)(src);
            const float4 v1 = *(const float4*)(src + 4);
            float* srow = &stg[u][l >> 1][(l & 1)*8];
            srow[0]=v0.x; srow[1]=v0.y; srow[2]=v0.z; srow[3]=v0.w;
            srow[4]=v1.x; srow[5]=v1.y; srow[6]=v1.z; srow[7]=v1.w;
            asm volatile("s_waitcnt lgkmcnt(0)" ::: "memory");
            const int d0 = (l >> 4) << 3, n = l & 15;
            ushort_t o[8];
            #pragma unroll
            for (int j = 0; j < 8; ++j) o[j] = f2h_s(stg[u][d0 + j][n]);
            *(uint4*)(dst + (size_t)l*8) = *(uint4*)o;
        } else if (c == 1344) {
            #pragma unroll
            for (int i = 0; i < 8; ++i) accz[l*8 + i] = 0.f;
        } else if (c < 1409) {
            const int b = c - 1345;
            const int n0 = np_[2*b], n1 = np_[2*b+1];
            float* dst = out + O_VALID + b*1024;
            #pragma unroll
            for (int i = 0; i < 16; ++i) {
                const int j = l*16 + i;
                const int t = j >> 5, s = j & 31;
                dst[j] = (t < n0 && s >= n0 && s < n0 + n1) ? 1.f : 0.f;
            }
        } else {
            // w4 fragments: N=16 (cols 0..3 real, rest zero), K=64 (2 ks)
            const int uu = c - 1409;
            const int h = uu >> 1, ks = uu & 1;
            const int n = l & 15;
            const int d0 = ks*32 + ((l >> 4) << 3);
            ushort_t o[8];
            #pragma unroll
            for (int j = 0; j < 8; ++j)
                o[j] = (n < 4) ? f2h_s(w4[(size_t)h*256 + (d0 + j)*4 + n]) : (ushort_t)0;
            *(uint4*)(bt4 + ((size_t)uu*64 + l)*8) = *(uint4*)o;
        }
        return;
    }

    // ---- AC path ----
    const int b = blockIdx.x & 63, hc = blockIdx.x >> 6;
    const int h = hc >> 1, isC = hc & 1;
    const int w4w = tid >> 6;
    const int lrow = l & 15, lko = l >> 4;

    {
        const float* eb = emb + (size_t)b*8192;
        #pragma unroll
        for (int j = 0; j < 16; ++j) {
            const int flat = j*256 + tid;
            const int row = flat >> 7, cp = flat & 127;
            const float2 v = *(const float2*)(eb + row*256 + cp*2);
            const uint_t p = cvt_pk_f16(v.x, v.y);
            const int byte = (row*512 + cp*4) ^ ((row & 7) << 4);
            *(uint_t*)(es + byte) = p;
        }
    }
    if (!isC && tid < 64) {
        const float* src = (tid < 32) ? (g1 + b*256 + tid*8) : (g2 + b*256 + (tid - 32)*8);
        const float4 v0 = *(const float4*)(src);
        const float4 v1 = *(const float4*)(src + 4);
        ushort_t o[8];
        o[0] = f2h_s(v0.x); o[1] = f2h_s(v0.y); o[2] = f2h_s(v0.z); o[3] = f2h_s(v0.w);
        o[4] = f2h_s(v1.x); o[5] = f2h_s(v1.y); o[6] = f2h_s(v1.z); o[7] = f2h_s(v1.w);
        *(uint4*)(gs + tid*8) = *(uint4*)o;
    }
    __syncthreads();

    f32x4 acc[2][8];
    #pragma unroll
    for (int mt = 0; mt < 2; ++mt)
        #pragma unroll
        for (int nt = 0; nt < 8; ++nt) acc[mt][nt] = (f32x4){0.f,0.f,0.f,0.f};

    const ushort_t* basef = bt0f + (size_t)h*(32*32*512) + (size_t)(w4w*8)*512 + (size_t)l*8;

    // emb K-steps: A -> W0 rows [0,256) (ks 0..7); C -> rows [256,512) (ks 8..15)
    {
        const int ksE0 = isC ? 8 : 0;
        for (int kk = 0; kk < 8; ++kk) {
            half8 bfv[8];
            const ushort_t* bp = basef + (size_t)(ksE0 + kk)*16384;
            #pragma unroll
            for (int nt = 0; nt < 8; ++nt) bfv[nt] = *(const half8*)(bp + nt*512);
            const int o = (lrow*512 + kk*64 + lko*16) ^ ((lrow & 7) << 4);
            const half8 a0 = *(const half8*)(es + o);
            const half8 a1 = *(const half8*)(es + o + 8192);
            __builtin_amdgcn_s_setprio(1);
            #pragma unroll
            for (int nt = 0; nt < 8; ++nt) {
                acc[0][nt] = __builtin_amdgcn_mfma_f32_16x16x32_f16(a0, bfv[nt], acc[0][nt], 0, 0, 0);
                acc[1][nt] = __builtin_amdgcn_mfma_f32_16x16x32_f16(a1, bfv[nt], acc[1][nt], 0, 0, 0);
            }
            __builtin_amdgcn_s_setprio(0);
        }
    }
    // g K-steps (A only): rows [512,1024) (ks 16..31); A-fragment row-uniform
    if (!isC) {
        for (int kk = 0; kk < 16; ++kk) {
            half8 bfv[8];
            const ushort_t* bp = basef + (size_t)(16 + kk)*16384;
            #pragma unroll
            for (int nt = 0; nt < 8; ++nt) bfv[nt] = *(const half8*)(bp + nt*512);
            const half8 ag = *(const half8*)(gs + kk*32 + lko*8);
            __builtin_amdgcn_s_setprio(1);
            #pragma unroll
            for (int nt = 0; nt < 8; ++nt) {
                acc[0][nt] = __builtin_amdgcn_mfma_f32_16x16x32_f16(ag, bfv[nt], acc[0][nt], 0, 0, 0);
                acc[1][nt] = __builtin_amdgcn_mfma_f32_16x16x32_f16(ag, bfv[nt], acc[1][nt], 0, 0, 0);
            }
            __builtin_amdgcn_s_setprio(0);
        }
    }

    ushort_t* dst = (isC ? Cbf : Abf) + (size_t)(h*64 + b)*32*512;
    #pragma unroll
    for (int nt = 0; nt < 8; ++nt) {
        const int col = (w4w*8 + nt)*16 + lrow;
        const float g = isC ? 0.f : b0[h*512 + col];
        #pragma unroll
        for (int mt = 0; mt < 2; ++mt)
            #pragma unroll
            for (int r = 0; r < 4; ++r) {
                const int row = mt*16 + lko*4 + r;
                dst[row*512 + col] = f2h_s(acc[mt][nt][r] + g);
            }
    }
}

// ================= K-MLP: M=64 fused MLP, 8 waves, 64KB LDS, fp16 pipeline =================
// logical id x (after XCD swizzle): x<1024: h=3, b=x>>4, t0=(x&15)*2   (rows = 2t x 32s)
//            x>=1024: y=x-1024, h=y>>8, b=(y>>2)&63, t0=(y&3)*4 (rows = 4t x 16s window)
// LDS 64KB: X0 [64][512] f16 @0; X1 [64][256] @0 overlay; X2 [64][128] @49152;
//           X3h f16 [64][64] @32768.
__global__ __launch_bounds__(512, 2) void k_mlp(
    const ushort_t* __restrict__ Abf, const ushort_t* __restrict__ Cbf,
    const ushort_t* __restrict__ bt1, const ushort_t* __restrict__ bt2,
    const ushort_t* __restrict__ bt3, const ushort_t* __restrict__ bt4,
    const float* __restrict__ b1, const float* __restrict__ b2, const float* __restrict__ b3,
    const float* __restrict__ b4,
    const int* __restrict__ np_, float* __restrict__ out, float* __restrict__ accbuf)
{
    // T1 XCD-aware swizzle: grid 1792 = 8 * 224 (bijective).
    const int bid = blockIdx.x;
    const int x = (bid & 7) * 224 + (bid >> 3);
    const bool isH3 = (x < 1024);
    int h, b, t0;
    int n0 = 0, n1 = 0;
    if (isH3) {
        h = 3; b = x >> 4; t0 = (x & 15) * 2;
    } else {
        const int y = x - 1024;
        h = y >> 8; b = (y >> 2) & 63; t0 = (y & 3) * 4;
        n0 = np_[2*b]; n1 = np_[2*b+1];
        if (t0 >= n0) return;
    }

    __shared__ __align__(16) char smem[65536];
    char* X   = smem;
    char* X2  = smem + 49152;
    char* X3h = smem + 32768;

    const int tid = threadIdx.x;
    const int l = tid & 63, w = tid >> 6;
    const int lrow = l & 15, lko = l >> 4;
    const size_t hb = (size_t)(h*64 + b);
    const uint4* Arows = (const uint4*)(Abf + hb*32*512);   // 64 uint4 per row
    const uint4* Crows = (const uint4*)(Cbf + hb*32*512);

    // biases (folded into accumulator init)
    const float bias1_0 = b1[h*256 + (w*2 + 0)*16 + lrow];
    const float bias1_1 = b1[h*256 + (w*2 + 1)*16 + lrow];
    const float bias2v  = b2[h*128 + w*16 + lrow];
    const float bias3v  = b3[h*64 + (w & 3)*16 + lrow];
    const float bias4v  = b4[h*4 + (lrow & 3)];

    // ---- prefetch first layer1 B-frags (independent of build) ----
    const ushort_t* bp1 = bt1 + (size_t)(h*256 + w*2)*512 + (size_t)l*8;
    half8 bb[2][2];
    bb[0][0] = *(const half8*)(bp1);
    bb[0][1] = *(const half8*)(bp1 + 512);

    // ---- build full X0 = relu(A'[t] + C[s]) : [64][512] f16, stride 1024B, swizzled ----
    #pragma unroll
    for (int i = 0; i < 8; ++i) {
        const int flat = i*512 + tid;        // [64 rows][64 uint4]
        const int row = flat >> 6, q4 = flat & 63;
        int trow, crow;
        if (isH3) { trow = t0 + (row >> 5); crow = row & 31; }
        else      { trow = t0 + (row >> 4); crow = n0 + (row & 15); }
        const uint4 aa = Arows[(size_t)trow*64 + q4];
        const uint4 cc = Crows[(size_t)crow*64 + q4];
        uint4 v;
        v.x = hadd2_relu(aa.x, cc.x);
        v.y = hadd2_relu(aa.y, cc.y);
        v.z = hadd2_relu(aa.z, cc.z);
        v.w = hadd2_relu(aa.w, cc.w);
        *(uint4*)(X + ((row*1024 + q4*16) ^ ((row & 7) << 4))) = v;
    }
    __syncthreads();                                           // [bar 1]

    // ---- layer1: K=512 (16 ks), M=64, N=256; wave owns 2 nt; acc init = bias ----
    f32x4 acc1[4][2];
    #pragma unroll
    for (int mt = 0; mt < 4; ++mt) {
        acc1[mt][0] = (f32x4){bias1_0, bias1_0, bias1_0, bias1_0};
        acc1[mt][1] = (f32x4){bias1_1, bias1_1, bias1_1, bias1_1};
    }

    #pragma unroll
    for (int ks = 0; ks < 16; ++ks) {
        if (ks < 15) {
            bb[(ks+1)&1][0] = *(const half8*)(bp1 + (size_t)(ks+1)*8192);
            bb[(ks+1)&1][1] = *(const half8*)(bp1 + (size_t)(ks+1)*8192 + 512);
        }
        const half8 bf0 = bb[ks&1][0];
        const half8 bf1 = bb[ks&1][1];
        __builtin_amdgcn_s_setprio(1);
        #pragma unroll
        for (int mt = 0; mt < 4; ++mt) {
            const half8 a0 = *(const half8*)(X + (((mt*16 + lrow)*1024 + ks*64 + lko*16) ^ ((lrow & 7) << 4)));
            acc1[mt][0] = __builtin_amdgcn_mfma_f32_16x16x32_f16(a0, bf0, acc1[mt][0], 0, 0, 0);
            acc1[mt][1] = __builtin_amdgcn_mfma_f32_16x16x32_f16(a0, bf1, acc1[mt][1], 0, 0, 0);
        }
        __builtin_amdgcn_s_setprio(0);
    }
    __syncthreads();                                           // [bar 2] X0 reads done

    // ---- X1 write (overlays X0 @0..32K): [64][256] f16 stride 512B ----
    #pragma unroll
    for (int nt = 0; nt < 2; ++nt) {
        const int col = (w*2 + nt)*16 + lrow;
        #pragma unroll
        for (int mt = 0; mt < 4; ++mt)
            #pragma unroll
            for (int r = 0; r < 4; ++r) {
                const int row = mt*16 + lko*4 + r;
                *(ushort_t*)(X + ((row*512 + col*2) ^ ((row & 7) << 4))) =
                    f2h_s(fmaxf(acc1[mt][nt][r], 0.f));
            }
    }
    __syncthreads();                                           // [bar 3]

    // ---- layer2: K=256, N=128; wave owns nt = w; X2 write @49152 (disjoint, no bar) ----
    f32x4 acc2[4];
    #pragma unroll
    for (int mt = 0; mt < 4; ++mt) acc2[mt] = (f32x4){bias2v, bias2v, bias2v, bias2v};
    {
        const ushort_t* bp = bt2 + (size_t)(h*64 + w)*512 + (size_t)l*8;
        half8 b2b[2];
        b2b[0] = *(const half8*)(bp);
        #pragma unroll
        for (int ks = 0; ks < 8; ++ks) {
            if (ks < 7) b2b[(ks+1)&1] = *(const half8*)(bp + (size_t)(ks+1)*4096);
            __builtin_amdgcn_s_setprio(1);
            #pragma unroll
            for (int mt = 0; mt < 4; ++mt) {
                const half8 a0 = *(const half8*)(X + (((mt*16 + lrow)*512 + ks*64 + lko*16) ^ ((lrow & 7) << 4)));
                acc2[mt] = __builtin_amdgcn_mfma_f32_16x16x32_f16(a0, b2b[ks&1], acc2[mt], 0, 0, 0);
            }
            __builtin_amdgcn_s_setprio(0);
        }
    }
    {
        const int col = w*16 + lrow;
        #pragma unroll
        for (int mt = 0; mt < 4; ++mt)
            #pragma unroll
            for (int r = 0; r < 4; ++r) {
                const int row = mt*16 + lko*4 + r;
                *(ushort_t*)(X2 + ((row*256 + col*2) ^ ((row & 7) << 4))) =
                    f2h_s(fmaxf(acc2[mt][r], 0.f));
            }
    }
    __syncthreads();                                           // [bar 4]

    // ---- layer3: K=128, N=64; wave = (nt=w&3, mhalf=w>>2); X3h f16 @32768 (disjoint) ----
    const int mhalf = w >> 2;
    f32x4 acc3[2];
    acc3[0] = (f32x4){bias3v, bias3v, bias3v, bias3v};
    acc3[1] = (f32x4){bias3v, bias3v, bias3v, bias3v};
    {
        const ushort_t* bp = bt3 + (size_t)(h*16 + (w & 3))*512 + (size_t)l*8;
        #pragma unroll
        for (int ks = 0; ks < 4; ++ks) {
            const half8 bf = *(const half8*)(bp + (size_t)ks*2048);
            __builtin_amdgcn_s_setprio(1);
            #pragma unroll
            for (int mi = 0; mi < 2; ++mi) {
                const int mt = mhalf*2 + mi;
                const half8 a0 = *(const half8*)(X2 + (((mt*16 + lrow)*256 + ks*64 + lko*16) ^ ((lrow & 7) << 4)));
                acc3[mi] = __builtin_amdgcn_mfma_f32_16x16x32_f16(a0, bf, acc3[mi], 0, 0, 0);
            }
            __builtin_amdgcn_s_setprio(0);
        }
    }
    {
        const int col = (w & 3)*16 + lrow;
        #pragma unroll
        for (int mi = 0; mi < 2; ++mi) {
            const int mt = mhalf*2 + mi;
            #pragma unroll
            for (int r = 0; r < 4; ++r) {
                const int row = mt*16 + lko*4 + r;
                *(ushort_t*)(X3h + ((row*128 + col*2) ^ ((row & 7) << 4))) =
                    f2h_s(fmaxf(acc3[mi][r], 0.f));
            }
        }
    }
    __syncthreads();                                           // [bar 5]

    // ---- layer4 via MFMA: M=64, K=64, N=16 (cols 0..3 real); waves 0..3, direct output ----
    if (w < 4) {
        const int mt = w;
        f32x4 acc4 = (f32x4){bias4v, bias4v, bias4v, bias4v};
        const ushort_t* bp = bt4 + (size_t)(h*2)*512 + (size_t)l*8;
        #pragma unroll
        for (int ks = 0; ks < 2; ++ks) {
            const half8 bf = *(const half8*)(bp + (size_t)ks*512);
            const half8 a0 = *(const half8*)(X3h + (((mt*16 + lrow)*128 + ks*64 + lko*16) ^ ((lrow & 7) << 4)));
            acc4 = __builtin_amdgcn_mfma_f32_16x16x32_f16(a0, bf, acc4, 0, 0, 0);
        }

        if (isH3) {
            if (lrow == 0) {
                #pragma unroll
                for (int r = 0; r < 4; ++r) {
                    const int row = mt*16 + lko*4 + r;
                    out[O_PLANE + b*1024 + (t0 + (row >> 5))*32 + (row & 31)] =
                        1.f / (1.f + expf(-acc4[r]));
                }
            }
        } else {
            const int nj = (h == 0) ? 1 : ((h == 1) ? 4 : 3);
            float v = 0.f;
            #pragma unroll
            for (int r = 0; r < 4; ++r) {
                const int row = mt*16 + lko*4 + r;
                const int tq = row >> 4, sr = row & 15;
                if ((t0 + tq) < n0 && sr < n1) v += acc4[r];
            }
            v += __shfl_down(v, 32);
            v += __shfl_down(v, 16);
            if (lko == 0 && lrow < nj) {
                const int slot = (h == 0) ? 0 : ((h == 1) ? 1 + lrow : 5 + lrow);
                atomicAdd(&accbuf[b*8 + slot], v);
            }
        }
    }
}

// ================= K-final: finalize scalar reductions =================
__global__ __launch_bounds__(512) void k_final(
    const int* __restrict__ np_, const float* __restrict__ acc, float* __restrict__ out)
{
    const int tid = threadIdx.x;
    const int b = tid >> 3, sl = tid & 7;
    const int n0 = np_[2*b], n1 = np_[2*b+1];
    const float pf = (float)(n0 * n1);
    const float v = acc[b*8 + sl] / pf;
    if (sl == 0)      out[O_CAM + b] = 1.f / (1.f + expf(-v));
    else if (sl <= 4) out[O_ROT + b*4 + (sl - 1)] = v;
    else              out[O_TRANS + b*3 + (sl - 5)] = v;
}

extern "C" void kernel_launch(void* const* d_in, const int* in_sizes, int n_in,
                              void* d_out, int out_size, void* d_ws, size_t ws_size,
                              hipStream_t stream) {
    (void)in_sizes; (void)n_in; (void)out_size; (void)ws_size;
    const float* emb = (const float*)d_in[0];
    const int*   np_ = (const int*)d_in[1];
    const float* w0  = (const float*)d_in[2];
    const float* b0  = (const float*)d_in[3];
    const float* w1  = (const float*)d_in[4];
    const float* b1  = (const float*)d_in[5];
    const float* w2  = (const float*)d_in[6];
    const float* b2  = (const float*)d_in[7];
    const float* w3  = (const float*)d_in[8];
    const float* b3  = (const float*)d_in[9];
    const float* w4  = (const float*)d_in[10];
    const float* b4  = (const float*)d_in[11];

    char* W = (char*)d_ws;
    float* out = (float*)d_out;
    float*    g1   = (float*)(W + B_G1);
    float*    g2   = (float*)(W + B_G2);
    float*    acc  = (float*)(W + B_ACC);
    ushort_t* Abf  = (ushort_t*)(W + B_ABF);
    ushort_t* Cbf  = (ushort_t*)(W + B_CBF);
    ushort_t* bt1  = (ushort_t*)(W + B_BT1);
    ushort_t* bt2  = (ushort_t*)(W + B_BT2);
    ushort_t* bt3  = (ushort_t*)(W + B_BT3);
    ushort_t* bt0f = (ushort_t*)(W + B_BT0F);
    ushort_t* bt4  = (ushort_t*)(W + B_BT4);

    k_prepA<<<1040, 256, 0, stream>>>(emb, np_, w0, bt0f, g1, g2);
    k_ACp<<<867, 256, 0, stream>>>(emb, bt0f, g1, g2, b0, Abf, Cbf,
                                   w1, w2, w3, w4, bt1, bt2, bt3, bt4, np_, acc, out);
    k_mlp<<<1792, 512, 0, stream>>>(Abf, Cbf, bt1, bt2, bt3, bt4,
                                    b1, b2, b3, b4, np_, out, acc);
    k_final<<<1, 512, 0, stream>>>(np_, acc, out);
}

// Round 16
// 84.556 us; speedup vs baseline: 1.0945x; 1.0141x over previous
//
#include <hip/hip_runtime.h>

typedef float f32x4 __attribute__((ext_vector_type(4)));
typedef _Float16 half8 __attribute__((ext_vector_type(8)));
typedef unsigned short ushort_t;
typedef unsigned int uint_t;

// (B,T,D,H) = (64, 32, 256, 4); DIMS = [1024, 512, 256, 128, 64, 4]
constexpr int O_CAM   = 0;
constexpr int O_ROT   = 64;
constexpr int O_TRANS = 320;
constexpr int O_PLANE = 512;
constexpr int O_VALID = 66048;

// Workspace layout (byte offsets)
constexpr size_t B_G1   = 0;         // f32 [64][256]
constexpr size_t B_G2   = 65536;     // f32 [64][256]
constexpr size_t B_ACC  = 131072;    // f32 [64][8]
constexpr size_t B_ABF  = 133120;    // f16 [4][64][32][512]  (A' = emb@W0a + G + b0)
constexpr size_t B_CBF  = 8521728;   // f16 [4][64][32][512]
constexpr size_t B_BT1  = 16910336;  // f16 frag [4][16ks][16nt][64][8]
constexpr size_t B_BT2  = 17958912;  // f16 frag [4][8][8][64][8]
constexpr size_t B_BT3  = 18221056;  // f16 frag [4][4][4][64][8]
constexpr size_t B_BT0F = 18286592;  // f16 frag [4h][32ks][32nt][64][8]  (full W0)
constexpr size_t B_BT4  = 22480896;  // f16 frag [4h][2ks][64][8]  (w4, N=16 padded)
// end = 22489088 bytes (~22.5 MB)

// f32 -> f16 bits, RNE
__device__ __forceinline__ ushort_t f2h_s(float f) {
    union { _Float16 h; ushort_t u; } cvt;
    cvt.h = (_Float16)f;
    return cvt.u;
}

// packed f32x2 -> f16x2 (RTZ), 1 VALU op
__device__ __forceinline__ uint_t cvt_pk_f16(float lo, float hi) {
    uint_t r;
    asm("v_cvt_pkrtz_f16_f32 %0, %1, %2" : "=v"(r) : "v"(lo), "v"(hi));
    return r;
}

// packed fp16: relu(a + c) in 2 VALU ops
__device__ __forceinline__ uint_t hadd2_relu(uint_t a, uint_t c) {
    uint_t r;
    asm("v_pk_add_f16 %0, %1, %2\n\tv_pk_max_f16 %0, %0, 0"
        : "=&v"(r) : "v"(a), "v"(c));
    return r;
}

// ================= K-prep: ALL weight fragments + g means + acc zero + valid mask =================
// unit c: [0,4096) W0 frags | [4096,4160) g means | [4160,5504) w1/w2/w3 frags
//         | 5504 acc zero | [5505,5569) valid mask | [5569,5577) w4 frags.
// 4 units (waves) per 256-thread block. 1395 blocks.
__global__ __launch_bounds__(256) void k_prep(
    const float* __restrict__ emb, const int* __restrict__ np_,
    const float* __restrict__ w0, const float* __restrict__ w1,
    const float* __restrict__ w2, const float* __restrict__ w3,
    const float* __restrict__ w4,
    ushort_t* __restrict__ bt0f,
    ushort_t* __restrict__ bt1, ushort_t* __restrict__ bt2, ushort_t* __restrict__ bt3,
    ushort_t* __restrict__ bt4,
    float* __restrict__ g1, float* __restrict__ g2,
    float* __restrict__ accz, float* __restrict__ out)
{
    __shared__ float stg[4][32][18];
    const int l = threadIdx.x & 63;
    const int u = threadIdx.x >> 6;
    int c = blockIdx.x * 4 + u;
    if (c >= 5577) return;
    if (c < 4096) {
        const int h = c >> 10, ks = (c >> 5) & 31, nt = c & 31;
        const float* src = w0 + ((size_t)h*1024 + ks*32 + (l >> 1))*512 + nt*16 + (l & 1)*8;
        const float4 v0 = *(const float4*)(src);
        const float4 v1 = *(const float4*)(src + 4);
        float* srow = &stg[u][l >> 1][(l & 1)*8];
        srow[0]=v0.x; srow[1]=v0.y; srow[2]=v0.z; srow[3]=v0.w;
        srow[4]=v1.x; srow[5]=v1.y; srow[6]=v1.z; srow[7]=v1.w;
        asm volatile("s_waitcnt lgkmcnt(0)" ::: "memory");
        const int d0 = (l >> 4) << 3, n = l & 15;
        ushort_t o[8];
        #pragma unroll
        for (int j = 0; j < 8; ++j) o[j] = f2h_s(stg[u][d0 + j][n]);
        *(uint4*)(bt0f + (size_t)c*512 + (size_t)l*8) = *(uint4*)o;
    } else if (c < 4160) {
        const int b = c - 4096;
        const int n0 = np_[2*b], n1 = np_[2*b+1];
        const float* e = emb + (size_t)b*8192;
        #pragma unroll
        for (int dd = 0; dd < 4; ++dd) {
            const int d = l + 64*dd;
            float a1 = 0.f, a2 = 0.f;
            for (int t = 0; t < 32; ++t) {
                float v = e[t*256 + d];
                if (t < n0) a1 += v;
                else if (t < n0 + n1) a2 += v;
            }
            g1[b*256 + d] = a1 / n0;
            g2[b*256 + d] = a2 / n1;
        }
    } else if (c < 5504) {
        c -= 4160;
        const float* w; ushort_t* dst; int K, N;
        if (c < 1024)      {           w = w1; dst = bt1 + (size_t)c*512; K = 512; N = 256; }
        else if (c < 1280) { c -= 1024; w = w2; dst = bt2 + (size_t)c*512; K = 256; N = 128; }
        else               { c -= 1280; w = w3; dst = bt3 + (size_t)c*512; K = 128; N = 64;  }
        const int NT = N/16, KS_NT = (K/32)*NT;
        const int h = c / KS_NT, rem = c % KS_NT, ks = rem / NT, nt = rem % NT;
        const float* src = w + ((size_t)(h*K + ks*32 + (l >> 1)))*N + nt*16 + (l & 1)*8;
        const float4 v0 = *(const float4*)(src);
        const float4 v1 = *(const float4*)(src + 4);
        float* srow = &stg[u][l >> 1][(l & 1)*8];
        srow[0]=v0.x; srow[1]=v0.y; srow[2]=v0.z; srow[3]=v0.w;
        srow[4]=v1.x; srow[5]=v1.y; srow[6]=v1.z; srow[7]=v1.w;
        asm volatile("s_waitcnt lgkmcnt(0)" ::: "memory");
        const int d0 = (l >> 4) << 3, n = l & 15;
        ushort_t o[8];
        #pragma unroll
        for (int j = 0; j < 8; ++j) o[j] = f2h_s(stg[u][d0 + j][n]);
        *(uint4*)(dst + (size_t)l*8) = *(uint4*)o;
    } else if (c == 5504) {
        #pragma unroll
        for (int i = 0; i < 8; ++i) accz[l*8 + i] = 0.f;
    } else if (c < 5569) {
        const int b = c - 5505;
        const int n0 = np_[2*b], n1 = np_[2*b+1];
        float* dst = out + O_VALID + b*1024;
        #pragma unroll
        for (int i = 0; i < 16; ++i) {
            const int j = l*16 + i;
            const int t = j >> 5, s = j & 31;
            dst[j] = (t < n0 && s >= n0 && s < n0 + n1) ? 1.f : 0.f;
        }
    } else {
        // w4 fragments: N=16 (cols 0..3 real, rest zero), K=64 (2 ks)
        const int uu = c - 5569;
        const int h = uu >> 1, ks = uu & 1;
        const int n = l & 15;
        const int d0 = ks*32 + ((l >> 4) << 3);
        ushort_t o[8];
        #pragma unroll
        for (int j = 0; j < 8; ++j)
            o[j] = (n < 4) ? f2h_s(w4[(size_t)h*256 + (d0 + j)*4 + n]) : (ushort_t)0;
        *(uint4*)(bt4 + ((size_t)uu*64 + l)*8) = *(uint4*)o;
    }
}

// ================= K-AC: pure A'/C GEMMs (f16 out), 512 blocks =================
// grid 512: b = x&63, hc = x>>6; hc = h*2 + isC.
// A' = emb@W0[0:256] + g1@W0[512:768] + g2@W0[768:1024] + b0 (K=768); C = emb@W0[256:512].
__global__ __launch_bounds__(256) void k_AC(
    const float* __restrict__ emb, const ushort_t* __restrict__ bt0f,
    const float* __restrict__ g1, const float* __restrict__ g2,
    const float* __restrict__ b0,
    ushort_t* __restrict__ Abf, ushort_t* __restrict__ Cbf)
{
    __shared__ __align__(16) char es[16384];       // f16 [32][256], stride 512B, swizzled
    __shared__ __align__(16) ushort_t gs[512];     // f16 [g1|g2]

    const int tid = threadIdx.x;
    const int l = tid & 63;
    const int b = blockIdx.x & 63, hc = blockIdx.x >> 6;
    const int h = hc >> 1, isC = hc & 1;
    const int w4w = tid >> 6;
    const int lrow = l & 15, lko = l >> 4;

    {
        const float* eb = emb + (size_t)b*8192;
        #pragma unroll
        for (int j = 0; j < 16; ++j) {
            const int flat = j*256 + tid;
            const int row = flat >> 7, cp = flat & 127;
            const float2 v = *(const float2*)(eb + row*256 + cp*2);
            const uint_t p = cvt_pk_f16(v.x, v.y);
            const int byte = (row*512 + cp*4) ^ ((row & 7) << 4);
            *(uint_t*)(es + byte) = p;
        }
    }
    if (!isC && tid < 64) {
        const float* src = (tid < 32) ? (g1 + b*256 + tid*8) : (g2 + b*256 + (tid - 32)*8);
        const float4 v0 = *(const float4*)(src);
        const float4 v1 = *(const float4*)(src + 4);
        ushort_t o[8];
        o[0] = f2h_s(v0.x); o[1] = f2h_s(v0.y); o[2] = f2h_s(v0.z); o[3] = f2h_s(v0.w);
        o[4] = f2h_s(v1.x); o[5] = f2h_s(v1.y); o[6] = f2h_s(v1.z); o[7] = f2h_s(v1.w);
        *(uint4*)(gs + tid*8) = *(uint4*)o;
    }
    __syncthreads();

    f32x4 acc[2][8];
    #pragma unroll
    for (int mt = 0; mt < 2; ++mt)
        #pragma unroll
        for (int nt = 0; nt < 8; ++nt) acc[mt][nt] = (f32x4){0.f,0.f,0.f,0.f};

    const ushort_t* basef = bt0f + (size_t)h*(32*32*512) + (size_t)(w4w*8)*512 + (size_t)l*8;

    // emb K-steps: A -> W0 rows [0,256) (ks 0..7); C -> rows [256,512) (ks 8..15)
    {
        const int ksE0 = isC ? 8 : 0;
        for (int kk = 0; kk < 8; ++kk) {
            half8 bfv[8];
            const ushort_t* bp = basef + (size_t)(ksE0 + kk)*16384;
            #pragma unroll
            for (int nt = 0; nt < 8; ++nt) bfv[nt] = *(const half8*)(bp + nt*512);
            const int o = (lrow*512 + kk*64 + lko*16) ^ ((lrow & 7) << 4);
            const half8 a0 = *(const half8*)(es + o);
            const half8 a1 = *(const half8*)(es + o + 8192);
            __builtin_amdgcn_s_setprio(1);
            #pragma unroll
            for (int nt = 0; nt < 8; ++nt) {
                acc[0][nt] = __builtin_amdgcn_mfma_f32_16x16x32_f16(a0, bfv[nt], acc[0][nt], 0, 0, 0);
                acc[1][nt] = __builtin_amdgcn_mfma_f32_16x16x32_f16(a1, bfv[nt], acc[1][nt], 0, 0, 0);
            }
            __builtin_amdgcn_s_setprio(0);
        }
    }
    // g K-steps (A only): rows [512,1024) (ks 16..31); A-fragment row-uniform
    if (!isC) {
        for (int kk = 0; kk < 16; ++kk) {
            half8 bfv[8];
            const ushort_t* bp = basef + (size_t)(16 + kk)*16384;
            #pragma unroll
            for (int nt = 0; nt < 8; ++nt) bfv[nt] = *(const half8*)(bp + nt*512);
            const half8 ag = *(const half8*)(gs + kk*32 + lko*8);
            __builtin_amdgcn_s_setprio(1);
            #pragma unroll
            for (int nt = 0; nt < 8; ++nt) {
                acc[0][nt] = __builtin_amdgcn_mfma_f32_16x16x32_f16(ag, bfv[nt], acc[0][nt], 0, 0, 0);
                acc[1][nt] = __builtin_amdgcn_mfma_f32_16x16x32_f16(ag, bfv[nt], acc[1][nt], 0, 0, 0);
            }
            __builtin_amdgcn_s_setprio(0);
        }
    }

    ushort_t* dst = (isC ? Cbf : Abf) + (size_t)(h*64 + b)*32*512;
    #pragma unroll
    for (int nt = 0; nt < 8; ++nt) {
        const int col = (w4w*8 + nt)*16 + lrow;
        const float g = isC ? 0.f : b0[h*512 + col];
        #pragma unroll
        for (int mt = 0; mt < 2; ++mt)
            #pragma unroll
            for (int r = 0; r < 4; ++r) {
                const int row = mt*16 + lko*4 + r;
                dst[row*512 + col] = f2h_s(acc[mt][nt][r] + g);
            }
    }
}

// ================= K-MLP: M=64 fused MLP, 8 waves, 64KB LDS, fp16 pipeline =================
// logical id x (after XCD swizzle): x<1024: h=3, b=x>>4, t0=(x&15)*2   (rows = 2t x 32s)
//            x>=1024: y=x-1024, h=y>>8, b=(y>>2)&63, t0=(y&3)*4 (rows = 4t x 16s window)
// LDS 64KB: X0 [64][512] f16 @0; X1 [64][256] @0 overlay; X2 [64][128] @49152;
//           X3h f16 [64][64] @32768.
__global__ __launch_bounds__(512, 2) void k_mlp(
    const ushort_t* __restrict__ Abf, const ushort_t* __restrict__ Cbf,
    const ushort_t* __restrict__ bt1, const ushort_t* __restrict__ bt2,
    const ushort_t* __restrict__ bt3, const ushort_t* __restrict__ bt4,
    const float* __restrict__ b1, const float* __restrict__ b2, const float* __restrict__ b3,
    const float* __restrict__ b4,
    const int* __restrict__ np_, float* __restrict__ out, float* __restrict__ accbuf)
{
    // T1 XCD-aware swizzle: grid 1792 = 8 * 224 (bijective).
    const int bid = blockIdx.x;
    const int x = (bid & 7) * 224 + (bid >> 3);
    const bool isH3 = (x < 1024);
    int h, b, t0;
    int n0 = 0, n1 = 0;
    if (isH3) {
        h = 3; b = x >> 4; t0 = (x & 15) * 2;
    } else {
        const int y = x - 1024;
        h = y >> 8; b = (y >> 2) & 63; t0 = (y & 3) * 4;
        n0 = np_[2*b]; n1 = np_[2*b+1];
        if (t0 >= n0) return;
    }

    __shared__ __align__(16) char smem[65536];
    char* X   = smem;
    char* X2  = smem + 49152;
    char* X3h = smem + 32768;

    const int tid = threadIdx.x;
    const int l = tid & 63, w = tid >> 6;
    const int lrow = l & 15, lko = l >> 4;
    const size_t hb = (size_t)(h*64 + b);
    const uint4* Arows = (const uint4*)(Abf + hb*32*512);   // 64 uint4 per row
    const uint4* Crows = (const uint4*)(Cbf + hb*32*512);

    // biases (folded into accumulator init)
    const float bias1_0 = b1[h*256 + (w*2 + 0)*16 + lrow];
    const float bias1_1 = b1[h*256 + (w*2 + 1)*16 + lrow];
    const float bias2v  = b2[h*128 + w*16 + lrow];
    const float bias3v  = b3[h*64 + (w & 3)*16 + lrow];
    const float bias4v  = b4[h*4 + (lrow & 3)];

    // ---- prefetch first layer1 B-frags (independent of build) ----
    const ushort_t* bp1 = bt1 + (size_t)(h*256 + w*2)*512 + (size_t)l*8;
    half8 bb[2][2];
    bb[0][0] = *(const half8*)(bp1);
    bb[0][1] = *(const half8*)(bp1 + 512);

    // ---- build full X0 = relu(A'[t] + C[s]) : [64][512] f16, stride 1024B, swizzled ----
    #pragma unroll
    for (int i = 0; i < 8; ++i) {
        const int flat = i*512 + tid;        // [64 rows][64 uint4]
        const int row = flat >> 6, q4 = flat & 63;
        int trow, crow;
        if (isH3) { trow = t0 + (row >> 5); crow = row & 31; }
        else      { trow = t0 + (row >> 4); crow = n0 + (row & 15); }
        const uint4 aa = Arows[(size_t)trow*64 + q4];
        const uint4 cc = Crows[(size_t)crow*64 + q4];
        uint4 v;
        v.x = hadd2_relu(aa.x, cc.x);
        v.y = hadd2_relu(aa.y, cc.y);
        v.z = hadd2_relu(aa.z, cc.z);
        v.w = hadd2_relu(aa.w, cc.w);
        *(uint4*)(X + ((row*1024 + q4*16) ^ ((row & 7) << 4))) = v;
    }
    __syncthreads();                                           // [bar 1]

    // ---- layer1: K=512 (16 ks), M=64, N=256; wave owns 2 nt; acc init = bias ----
    f32x4 acc1[4][2];
    #pragma unroll
    for (int mt = 0; mt < 4; ++mt) {
        acc1[mt][0] = (f32x4){bias1_0, bias1_0, bias1_0, bias1_0};
        acc1[mt][1] = (f32x4){bias1_1, bias1_1, bias1_1, bias1_1};
    }

    #pragma unroll
    for (int ks = 0; ks < 16; ++ks) {
        if (ks < 15) {
            bb[(ks+1)&1][0] = *(const half8*)(bp1 + (size_t)(ks+1)*8192);
            bb[(ks+1)&1][1] = *(const half8*)(bp1 + (size_t)(ks+1)*8192 + 512);
        }
        const half8 bf0 = bb[ks&1][0];
        const half8 bf1 = bb[ks&1][1];
        __builtin_amdgcn_s_setprio(1);
        #pragma unroll
        for (int mt = 0; mt < 4; ++mt) {
            const half8 a0 = *(const half8*)(X + (((mt*16 + lrow)*1024 + ks*64 + lko*16) ^ ((lrow & 7) << 4)));
            acc1[mt][0] = __builtin_amdgcn_mfma_f32_16x16x32_f16(a0, bf0, acc1[mt][0], 0, 0, 0);
            acc1[mt][1] = __builtin_amdgcn_mfma_f32_16x16x32_f16(a0, bf1, acc1[mt][1], 0, 0, 0);
        }
        __builtin_amdgcn_s_setprio(0);
    }
    __syncthreads();                                           // [bar 2] X0 reads done

    // ---- X1 write (overlays X0 @0..32K): [64][256] f16 stride 512B ----
    #pragma unroll
    for (int nt = 0; nt < 2; ++nt) {
        const int col = (w*2 + nt)*16 + lrow;
        #pragma unroll
        for (int mt = 0; mt < 4; ++mt)
            #pragma unroll
            for (int r = 0; r < 4; ++r) {
                const int row = mt*16 + lko*4 + r;
                *(ushort_t*)(X + ((row*512 + col*2) ^ ((row & 7) << 4))) =
                    f2h_s(fmaxf(acc1[mt][nt][r], 0.f));
            }
    }
    __syncthreads();                                           // [bar 3]

    // ---- layer2: K=256, N=128; wave owns nt = w; X2 write @49152 (disjoint, no bar) ----
    f32x4 acc2[4];
    #pragma unroll
    for (int mt = 0; mt < 4; ++mt) acc2[mt] = (f32x4){bias2v, bias2v, bias2v, bias2v};
    {
        const ushort_t* bp = bt2 + (size_t)(h*64 + w)*512 + (size_t)l*8;
        half8 b2b[2];
        b2b[0] = *(const half8*)(bp);
        #pragma unroll
        for (int ks = 0; ks < 8; ++ks) {
            if (ks < 7) b2b[(ks+1)&1] = *(const half8*)(bp + (size_t)(ks+1)*4096);
            __builtin_amdgcn_s_setprio(1);
            #pragma unroll
            for (int mt = 0; mt < 4; ++mt) {
                const half8 a0 = *(const half8*)(X + (((mt*16 + lrow)*512 + ks*64 + lko*16) ^ ((lrow & 7) << 4)));
                acc2[mt] = __builtin_amdgcn_mfma_f32_16x16x32_f16(a0, b2b[ks&1], acc2[mt], 0, 0, 0);
            }
            __builtin_amdgcn_s_setprio(0);
        }
    }
    {
        const int col = w*16 + lrow;
        #pragma unroll
        for (int mt = 0; mt < 4; ++mt)
            #pragma unroll
            for (int r = 0; r < 4; ++r) {
                const int row = mt*16 + lko*4 + r;
                *(ushort_t*)(X2 + ((row*256 + col*2) ^ ((row & 7) << 4))) =
                    f2h_s(fmaxf(acc2[mt][r], 0.f));
            }
    }
    __syncthreads();                                           // [bar 4]

    // ---- layer3: K=128, N=64; wave = (nt=w&3, mhalf=w>>2); X3h f16 @32768 (disjoint) ----
    const int mhalf = w >> 2;
    f32x4 acc3[2];
    acc3[0] = (f32x4){bias3v, bias3v, bias3v, bias3v};
    acc3[1] = (f32x4){bias3v, bias3v, bias3v, bias3v};
    {
        const ushort_t* bp = bt3 + (size_t)(h*16 + (w & 3))*512 + (size_t)l*8;
        #pragma unroll
        for (int ks = 0; ks < 4; ++ks) {
            const half8 bf = *(const half8*)(bp + (size_t)ks*2048);
            __builtin_amdgcn_s_setprio(1);
            #pragma unroll
            for (int mi = 0; mi < 2; ++mi) {
                const int mt = mhalf*2 + mi;
                const half8 a0 = *(const half8*)(X2 + (((mt*16 + lrow)*256 + ks*64 + lko*16) ^ ((lrow & 7) << 4)));
                acc3[mi] = __builtin_amdgcn_mfma_f32_16x16x32_f16(a0, bf, acc3[mi], 0, 0, 0);
            }
            __builtin_amdgcn_s_setprio(0);
        }
    }
    {
        const int col = (w & 3)*16 + lrow;
        #pragma unroll
        for (int mi = 0; mi < 2; ++mi) {
            const int mt = mhalf*2 + mi;
            #pragma unroll
            for (int r = 0; r < 4; ++r) {
                const int row = mt*16 + lko*4 + r;
                *(ushort_t*)(X3h + ((row*128 + col*2) ^ ((row & 7) << 4))) =
                    f2h_s(fmaxf(acc3[mi][r], 0.f));
            }
        }
    }
    __syncthreads();                                           // [bar 5]

    // ---- layer4 via MFMA: M=64, K=64, N=16 (cols 0..3 real); waves 0..3, direct output ----
    if (w < 4) {
        const int mt = w;
        f32x4 acc4 = (f32x4){bias4v, bias4v, bias4v, bias4v};
        const ushort_t* bp = bt4 + (size_t)(h*2)*512 + (size_t)l*8;
        #pragma unroll
        for (int ks = 0; ks < 2; ++ks) {
            const half8 bf = *(const half8*)(bp + (size_t)ks*512);
            const half8 a0 = *(const half8*)(X3h + (((mt*16 + lrow)*128 + ks*64 + lko*16) ^ ((lrow & 7) << 4)));
            acc4 = __builtin_amdgcn_mfma_f32_16x16x32_f16(a0, bf, acc4, 0, 0, 0);
        }

        if (isH3) {
            if (lrow == 0) {
                #pragma unroll
                for (int r = 0; r < 4; ++r) {
                    const int row = mt*16 + lko*4 + r;
                    out[O_PLANE + b*1024 + (t0 + (row >> 5))*32 + (row & 31)] =
                        1.f / (1.f + expf(-acc4[r]));
                }
            }
        } else {
            const int nj = (h == 0) ? 1 : ((h == 1) ? 4 : 3);
            float v = 0.f;
            #pragma unroll
            for (int r = 0; r < 4; ++r) {
                const int row = mt*16 + lko*4 + r;
                const int tq = row >> 4, sr = row & 15;
                if ((t0 + tq) < n0 && sr < n1) v += acc4[r];
            }
            v += __shfl_down(v, 32);
            v += __shfl_down(v, 16);
            if (lko == 0 && lrow < nj) {
                const int slot = (h == 0) ? 0 : ((h == 1) ? 1 + lrow : 5 + lrow);
                atomicAdd(&accbuf[b*8 + slot], v);
            }
        }
    }
}

// ================= K-final: finalize scalar reductions =================
__global__ __launch_bounds__(512) void k_final(
    const int* __restrict__ np_, const float* __restrict__ acc, float* __restrict__ out)
{
    const int tid = threadIdx.x;
    const int b = tid >> 3, sl = tid & 7;
    const int n0 = np_[2*b], n1 = np_[2*b+1];
    const float pf = (float)(n0 * n1);
    const float v = acc[b*8 + sl] / pf;
    if (sl == 0)      out[O_CAM + b] = 1.f / (1.f + expf(-v));
    else if (sl <= 4) out[O_ROT + b*4 + (sl - 1)] = v;
    else              out[O_TRANS + b*3 + (sl - 5)] = v;
}

extern "C" void kernel_launch(void* const* d_in, const int* in_sizes, int n_in,
                              void* d_out, int out_size, void* d_ws, size_t ws_size,
                              hipStream_t stream) {
    (void)in_sizes; (void)n_in; (void)out_size; (void)ws_size;
    const float* emb = (const float*)d_in[0];
    const int*   np_ = (const int*)d_in[1];
    const float* w0  = (const float*)d_in[2];
    const float* b0  = (const float*)d_in[3];
    const float* w1  = (const float*)d_in[4];
    const float* b1  = (const float*)d_in[5];
    const float* w2  = (const float*)d_in[6];
    const float* b2  = (const float*)d_in[7];
    const float* w3  = (const float*)d_in[8];
    const float* b3  = (const float*)d_in[9];
    const float* w4  = (const float*)d_in[10];
    const float* b4  = (const float*)d_in[11];

    char* W = (char*)d_ws;
    float* out = (float*)d_out;
    float*    g1   = (float*)(W + B_G1);
    float*    g2   = (float*)(W + B_G2);
    float*    acc  = (float*)(W + B_ACC);
    ushort_t* Abf  = (ushort_t*)(W + B_ABF);
    ushort_t* Cbf  = (ushort_t*)(W + B_CBF);
    ushort_t* bt1  = (ushort_t*)(W + B_BT1);
    ushort_t* bt2  = (ushort_t*)(W + B_BT2);
    ushort_t* bt3  = (ushort_t*)(W + B_BT3);
    ushort_t* bt0f = (ushort_t*)(W + B_BT0F);
    ushort_t* bt4  = (ushort_t*)(W + B_BT4);

    k_prep<<<1395, 256, 0, stream>>>(emb, np_, w0, w1, w2, w3, w4,
                                     bt0f, bt1, bt2, bt3, bt4, g1, g2, acc, out);
    k_AC<<<512, 256, 0, stream>>>(emb, bt0f, g1, g2, b0, Abf, Cbf);
    k_mlp<<<1792, 512, 0, stream>>>(Abf, Cbf, bt1, bt2, bt3, bt4,
                                    b1, b2, b3, b4, np_, out, acc);
    k_final<<<1, 512, 0, stream>>>(np_, acc, out);
}

// Round 17
// 84.382 us; speedup vs baseline: 1.0968x; 1.0021x over previous
//
#include <hip/hip_runtime.h>

typedef float f32x4 __attribute__((ext_vector_type(4)));
typedef _Float16 half8 __attribute__((ext_vector_type(8)));
typedef unsigned short ushort_t;
typedef unsigned int uint_t;

// (B,T,D,H) = (64, 32, 256, 4); DIMS = [1024, 512, 256, 128, 64, 4]
constexpr int O_CAM   = 0;
constexpr int O_ROT   = 64;
constexpr int O_TRANS = 320;
constexpr int O_PLANE = 512;
constexpr int O_VALID = 66048;

// Workspace layout (byte offsets)
constexpr size_t B_G1   = 0;         // f32 [64][256]
constexpr size_t B_G2   = 65536;     // f32 [64][256]
constexpr size_t B_ACC  = 131072;    // f32 [64][8]
constexpr size_t B_ABF  = 133120;    // f16 [4][64][32][512]  (A' = emb@W0a + G + b0)
constexpr size_t B_CBF  = 8521728;   // f16 [4][64][32][512]
constexpr size_t B_BT1  = 16910336;  // f16 frag [4][16ks][16nt][64][8]
constexpr size_t B_BT2  = 17958912;  // f16 frag [4][8][8][64][8]
constexpr size_t B_BT3  = 18221056;  // f16 frag [4][4][4][64][8]
constexpr size_t B_BT0F = 18286592;  // f16 frag [4h][32ks][32nt][64][8]  (full W0)
constexpr size_t B_BT4  = 22480896;  // f16 frag [4h][2ks][64][8]  (w4, N=16 padded)
// end = 22489088 bytes (~22.5 MB)

// f32 -> f16 bits, RNE
__device__ __forceinline__ ushort_t f2h_s(float f) {
    union { _Float16 h; ushort_t u; } cvt;
    cvt.h = (_Float16)f;
    return cvt.u;
}

// packed f32x2 -> f16x2 (RTZ), 1 VALU op
__device__ __forceinline__ uint_t cvt_pk_f16(float lo, float hi) {
    uint_t r;
    asm("v_cvt_pkrtz_f16_f32 %0, %1, %2" : "=v"(r) : "v"(lo), "v"(hi));
    return r;
}

// packed fp16: relu(a + c) in 2 VALU ops
__device__ __forceinline__ uint_t hadd2_relu(uint_t a, uint_t c) {
    uint_t r;
    asm("v_pk_add_f16 %0, %1, %2\n\tv_pk_max_f16 %0, %0, 0"
        : "=&v"(r) : "v"(a), "v"(c));
    return r;
}

// ================= K-prep: ALL weight fragments + g means + acc zero + valid mask =================
// unit c: [0,4096) W0 frags | [4096,4160) g means | [4160,5504) w1/w2/w3 frags
//         | 5504 acc zero | [5505,5569) valid mask | [5569,5577) w4 frags.
__global__ __launch_bounds__(256) void k_prep(
    const float* __restrict__ emb, const int* __restrict__ np_,
    const float* __restrict__ w0, const float* __restrict__ w1,
    const float* __restrict__ w2, const float* __restrict__ w3,
    const float* __restrict__ w4,
    ushort_t* __restrict__ bt0f,
    ushort_t* __restrict__ bt1, ushort_t* __restrict__ bt2, ushort_t* __restrict__ bt3,
    ushort_t* __restrict__ bt4,
    float* __restrict__ g1, float* __restrict__ g2,
    float* __restrict__ accz, float* __restrict__ out)
{
    __shared__ float stg[4][32][18];
    const int l = threadIdx.x & 63;
    const int u = threadIdx.x >> 6;
    int c = blockIdx.x * 4 + u;
    if (c >= 5577) return;
    if (c < 4096) {
        const int h = c >> 10, ks = (c >> 5) & 31, nt = c & 31;
        const float* src = w0 + ((size_t)h*1024 + ks*32 + (l >> 1))*512 + nt*16 + (l & 1)*8;
        const float4 v0 = *(const float4*)(src);
        const float4 v1 = *(const float4*)(src + 4);
        float* srow = &stg[u][l >> 1][(l & 1)*8];
        srow[0]=v0.x; srow[1]=v0.y; srow[2]=v0.z; srow[3]=v0.w;
        srow[4]=v1.x; srow[5]=v1.y; srow[6]=v1.z; srow[7]=v1.w;
        asm volatile("s_waitcnt lgkmcnt(0)" ::: "memory");
        const int d0 = (l >> 4) << 3, n = l & 15;
        ushort_t o[8];
        #pragma unroll
        for (int j = 0; j < 8; ++j) o[j] = f2h_s(stg[u][d0 + j][n]);
        *(uint4*)(bt0f + (size_t)c*512 + (size_t)l*8) = *(uint4*)o;
    } else if (c < 4160) {
        const int b = c - 4096;
        const int n0 = np_[2*b], n1 = np_[2*b+1];
        const float* e = emb + (size_t)b*8192;
        #pragma unroll
        for (int dd = 0; dd < 4; ++dd) {
            const int d = l + 64*dd;
            float a1 = 0.f, a2 = 0.f;
            for (int t = 0; t < 32; ++t) {
                float v = e[t*256 + d];
                if (t < n0) a1 += v;
                else if (t < n0 + n1) a2 += v;
            }
            g1[b*256 + d] = a1 / n0;
            g2[b*256 + d] = a2 / n1;
        }
    } else if (c < 5504) {
        c -= 4160;
        const float* w; ushort_t* dst; int K, N;
        if (c < 1024)      {           w = w1; dst = bt1 + (size_t)c*512; K = 512; N = 256; }
        else if (c < 1280) { c -= 1024; w = w2; dst = bt2 + (size_t)c*512; K = 256; N = 128; }
        else               { c -= 1280; w = w3; dst = bt3 + (size_t)c*512; K = 128; N = 64;  }
        const int NT = N/16, KS_NT = (K/32)*NT;
        const int h = c / KS_NT, rem = c % KS_NT, ks = rem / NT, nt = rem % NT;
        const float* src = w + ((size_t)(h*K + ks*32 + (l >> 1)))*N + nt*16 + (l & 1)*8;
        const float4 v0 = *(const float4*)(src);
        const float4 v1 = *(const float4*)(src + 4);
        float* srow = &stg[u][l >> 1][(l & 1)*8];
        srow[0]=v0.x; srow[1]=v0.y; srow[2]=v0.z; srow[3]=v0.w;
        srow[4]=v1.x; srow[5]=v1.y; srow[6]=v1.z; srow[7]=v1.w;
        asm volatile("s_waitcnt lgkmcnt(0)" ::: "memory");
        const int d0 = (l >> 4) << 3, n = l & 15;
        ushort_t o[8];
        #pragma unroll
        for (int j = 0; j < 8; ++j) o[j] = f2h_s(stg[u][d0 + j][n]);
        *(uint4*)(dst + (size_t)l*8) = *(uint4*)o;
    } else if (c == 5504) {
        #pragma unroll
        for (int i = 0; i < 8; ++i) accz[l*8 + i] = 0.f;
    } else if (c < 5569) {
        const int b = c - 5505;
        const int n0 = np_[2*b], n1 = np_[2*b+1];
        float* dst = out + O_VALID + b*1024;
        #pragma unroll
        for (int i = 0; i < 16; ++i) {
            const int j = l*16 + i;
            const int t = j >> 5, s = j & 31;
            dst[j] = (t < n0 && s >= n0 && s < n0 + n1) ? 1.f : 0.f;
        }
    } else {
        // w4 fragments: N=16 (cols 0..3 real, rest zero), K=64 (2 ks)
        const int uu = c - 5569;
        const int h = uu >> 1, ks = uu & 1;
        const int n = l & 15;
        const int d0 = ks*32 + ((l >> 4) << 3);
        ushort_t o[8];
        #pragma unroll
        for (int j = 0; j < 8; ++j)
            o[j] = (n < 4) ? f2h_s(w4[(size_t)h*256 + (d0 + j)*4 + n]) : (ushort_t)0;
        *(uint4*)(bt4 + ((size_t)uu*64 + l)*8) = *(uint4*)o;
    }
}

// ================= K-AC: pure A'/C GEMMs (f16 out), 512 blocks =================
__global__ __launch_bounds__(256) void k_AC(
    const float* __restrict__ emb, const ushort_t* __restrict__ bt0f,
    const float* __restrict__ g1, const float* __restrict__ g2,
    const float* __restrict__ b0,
    ushort_t* __restrict__ Abf, ushort_t* __restrict__ Cbf)
{
    __shared__ __align__(16) char es[16384];       // f16 [32][256], stride 512B, swizzled
    __shared__ __align__(16) ushort_t gs[512];     // f16 [g1|g2]

    const int tid = threadIdx.x;
    const int l = tid & 63;
    const int b = blockIdx.x & 63, hc = blockIdx.x >> 6;
    const int h = hc >> 1, isC = hc & 1;
    const int w4w = tid >> 6;
    const int lrow = l & 15, lko = l >> 4;

    {
        const float* eb = emb + (size_t)b*8192;
        #pragma unroll
        for (int j = 0; j < 16; ++j) {
            const int flat = j*256 + tid;
            const int row = flat >> 7, cp = flat & 127;
            const float2 v = *(const float2*)(eb + row*256 + cp*2);
            const uint_t p = cvt_pk_f16(v.x, v.y);
            const int byte = (row*512 + cp*4) ^ ((row & 7) << 4);
            *(uint_t*)(es + byte) = p;
        }
    }
    if (!isC && tid < 64) {
        const float* src = (tid < 32) ? (g1 + b*256 + tid*8) : (g2 + b*256 + (tid - 32)*8);
        const float4 v0 = *(const float4*)(src);
        const float4 v1 = *(const float4*)(src + 4);
        ushort_t o[8];
        o[0] = f2h_s(v0.x); o[1] = f2h_s(v0.y); o[2] = f2h_s(v0.z); o[3] = f2h_s(v0.w);
        o[4] = f2h_s(v1.x); o[5] = f2h_s(v1.y); o[6] = f2h_s(v1.z); o[7] = f2h_s(v1.w);
        *(uint4*)(gs + tid*8) = *(uint4*)o;
    }
    __syncthreads();

    f32x4 acc[2][8];
    #pragma unroll
    for (int mt = 0; mt < 2; ++mt)
        #pragma unroll
        for (int nt = 0; nt < 8; ++nt) acc[mt][nt] = (f32x4){0.f,0.f,0.f,0.f};

    const ushort_t* basef = bt0f + (size_t)h*(32*32*512) + (size_t)(w4w*8)*512 + (size_t)l*8;

    // emb K-steps: A -> W0 rows [0,256) (ks 0..7); C -> rows [256,512) (ks 8..15)
    {
        const int ksE0 = isC ? 8 : 0;
        for (int kk = 0; kk < 8; ++kk) {
            half8 bfv[8];
            const ushort_t* bp = basef + (size_t)(ksE0 + kk)*16384;
            #pragma unroll
            for (int nt = 0; nt < 8; ++nt) bfv[nt] = *(const half8*)(bp + nt*512);
            const int o = (lrow*512 + kk*64 + lko*16) ^ ((lrow & 7) << 4);
            const half8 a0 = *(const half8*)(es + o);
            const half8 a1 = *(const half8*)(es + o + 8192);
            __builtin_amdgcn_s_setprio(1);
            #pragma unroll
            for (int nt = 0; nt < 8; ++nt) {
                acc[0][nt] = __builtin_amdgcn_mfma_f32_16x16x32_f16(a0, bfv[nt], acc[0][nt], 0, 0, 0);
                acc[1][nt] = __builtin_amdgcn_mfma_f32_16x16x32_f16(a1, bfv[nt], acc[1][nt], 0, 0, 0);
            }
            __builtin_amdgcn_s_setprio(0);
        }
    }
    // g K-steps (A only): rows [512,1024) (ks 16..31); A-fragment row-uniform
    if (!isC) {
        for (int kk = 0; kk < 16; ++kk) {
            half8 bfv[8];
            const ushort_t* bp = basef + (size_t)(16 + kk)*16384;
            #pragma unroll
            for (int nt = 0; nt < 8; ++nt) bfv[nt] = *(const half8*)(bp + nt*512);
            const half8 ag = *(const half8*)(gs + kk*32 + lko*8);
            __builtin_amdgcn_s_setprio(1);
            #pragma unroll
            for (int nt = 0; nt < 8; ++nt) {
                acc[0][nt] = __builtin_amdgcn_mfma_f32_16x16x32_f16(ag, bfv[nt], acc[0][nt], 0, 0, 0);
                acc[1][nt] = __builtin_amdgcn_mfma_f32_16x16x32_f16(ag, bfv[nt], acc[1][nt], 0, 0, 0);
            }
            __builtin_amdgcn_s_setprio(0);
        }
    }

    ushort_t* dst = (isC ? Cbf : Abf) + (size_t)(h*64 + b)*32*512;
    #pragma unroll
    for (int nt = 0; nt < 8; ++nt) {
        const int col = (w4w*8 + nt)*16 + lrow;
        const float g = isC ? 0.f : b0[h*512 + col];
        #pragma unroll
        for (int mt = 0; mt < 2; ++mt)
            #pragma unroll
            for (int r = 0; r < 4; ++r) {
                const int row = mt*16 + lko*4 + r;
                dst[row*512 + col] = f2h_s(acc[mt][nt][r] + g);
            }
    }
}

// ================= K-MLP: M=64 fused MLP, 8 waves, 80KB LDS, 4 barriers =================
// logical id x (after XCD swizzle): x<1024: h=3, b=x>>4, t0=(x&15)*2
//            x>=1024: y=x-1024, h=y>>8, b=(y>>2)&63, t0=(y&3)*4
// LDS 80KB: X0 [64][512] f16 @0 (64KB); X1 [64][256] f16 @65536 (16KB, DISJOINT);
//           X2 [64][128] @0 (X0 dead); X3h f16 [64][64] @16384.
__global__ __launch_bounds__(512, 2) void k_mlp(
    const ushort_t* __restrict__ Abf, const ushort_t* __restrict__ Cbf,
    const ushort_t* __restrict__ bt1, const ushort_t* __restrict__ bt2,
    const ushort_t* __restrict__ bt3, const ushort_t* __restrict__ bt4,
    const float* __restrict__ b1, const float* __restrict__ b2, const float* __restrict__ b3,
    const float* __restrict__ b4,
    const int* __restrict__ np_, float* __restrict__ out, float* __restrict__ accbuf)
{
    // T1 XCD-aware swizzle: grid 1792 = 8 * 224 (bijective).
    const int bid = blockIdx.x;
    const int x = (bid & 7) * 224 + (bid >> 3);
    const bool isH3 = (x < 1024);
    int h, b, t0;
    int n0 = 0, n1 = 0;
    if (isH3) {
        h = 3; b = x >> 4; t0 = (x & 15) * 2;
    } else {
        const int y = x - 1024;
        h = y >> 8; b = (y >> 2) & 63; t0 = (y & 3) * 4;
        n0 = np_[2*b]; n1 = np_[2*b+1];
        if (t0 >= n0) return;
    }

    __shared__ __align__(16) char smem[81920];
    char* X   = smem;              // X0 [64][512] f16, 64KB
    char* X1n = smem + 65536;      // X1 [64][256] f16, 16KB (disjoint from X0)
    char* X2  = smem;              // X2 [64][128] f16 @0 (X0 dead after layer1)
    char* X3h = smem + 16384;      // X3 [64][64] f16 (disjoint from X2)

    const int tid = threadIdx.x;
    const int l = tid & 63, w = tid >> 6;
    const int lrow = l & 15, lko = l >> 4;
    const size_t hb = (size_t)(h*64 + b);
    const uint4* Arows = (const uint4*)(Abf + hb*32*512);   // 64 uint4 per row
    const uint4* Crows = (const uint4*)(Cbf + hb*32*512);

    // biases (folded into accumulator init)
    const float bias1_0 = b1[h*256 + (w*2 + 0)*16 + lrow];
    const float bias1_1 = b1[h*256 + (w*2 + 1)*16 + lrow];
    const float bias2v  = b2[h*128 + w*16 + lrow];
    const float bias3v  = b3[h*64 + (w & 3)*16 + lrow];
    const float bias4v  = b4[h*4 + (lrow & 3)];

    // ---- prefetch first layer1 B-frags (independent of build) ----
    const ushort_t* bp1 = bt1 + (size_t)(h*256 + w*2)*512 + (size_t)l*8;
    half8 bb[2][2];
    bb[0][0] = *(const half8*)(bp1);
    bb[0][1] = *(const half8*)(bp1 + 512);

    // ---- build full X0 = relu(A'[t] + C[s]) : [64][512] f16, stride 1024B, swizzled ----
    #pragma unroll
    for (int i = 0; i < 8; ++i) {
        const int flat = i*512 + tid;        // [64 rows][64 uint4]
        const int row = flat >> 6, q4 = flat & 63;
        int trow, crow;
        if (isH3) { trow = t0 + (row >> 5); crow = row & 31; }
        else      { trow = t0 + (row >> 4); crow = n0 + (row & 15); }
        const uint4 aa = Arows[(size_t)trow*64 + q4];
        const uint4 cc = Crows[(size_t)crow*64 + q4];
        uint4 v;
        v.x = hadd2_relu(aa.x, cc.x);
        v.y = hadd2_relu(aa.y, cc.y);
        v.z = hadd2_relu(aa.z, cc.z);
        v.w = hadd2_relu(aa.w, cc.w);
        *(uint4*)(X + ((row*1024 + q4*16) ^ ((row & 7) << 4))) = v;
    }
    __syncthreads();                                           // [bar 1] X0 ready

    // ---- layer1: K=512 (16 ks), M=64, N=256; wave owns 2 nt; acc init = bias ----
    f32x4 acc1[4][2];
    #pragma unroll
    for (int mt = 0; mt < 4; ++mt) {
        acc1[mt][0] = (f32x4){bias1_0, bias1_0, bias1_0, bias1_0};
        acc1[mt][1] = (f32x4){bias1_1, bias1_1, bias1_1, bias1_1};
    }

    #pragma unroll
    for (int ks = 0; ks < 16; ++ks) {
        if (ks < 15) {
            bb[(ks+1)&1][0] = *(const half8*)(bp1 + (size_t)(ks+1)*8192);
            bb[(ks+1)&1][1] = *(const half8*)(bp1 + (size_t)(ks+1)*8192 + 512);
        }
        const half8 bf0 = bb[ks&1][0];
        const half8 bf1 = bb[ks&1][1];
        __builtin_amdgcn_s_setprio(1);
        #pragma unroll
        for (int mt = 0; mt < 4; ++mt) {
            const half8 a0 = *(const half8*)(X + (((mt*16 + lrow)*1024 + ks*64 + lko*16) ^ ((lrow & 7) << 4)));
            acc1[mt][0] = __builtin_amdgcn_mfma_f32_16x16x32_f16(a0, bf0, acc1[mt][0], 0, 0, 0);
            acc1[mt][1] = __builtin_amdgcn_mfma_f32_16x16x32_f16(a0, bf1, acc1[mt][1], 0, 0, 0);
        }
        __builtin_amdgcn_s_setprio(0);
    }

    // ---- X1 write to DISJOINT region (no barrier needed before) ----
    #pragma unroll
    for (int nt = 0; nt < 2; ++nt) {
        const int col = (w*2 + nt)*16 + lrow;
        #pragma unroll
        for (int mt = 0; mt < 4; ++mt)
            #pragma unroll
            for (int r = 0; r < 4; ++r) {
                const int row = mt*16 + lko*4 + r;
                *(ushort_t*)(X1n + ((row*512 + col*2) ^ ((row & 7) << 4))) =
                    f2h_s(fmaxf(acc1[mt][nt][r], 0.f));
            }
    }
    __syncthreads();                                           // [bar 2] X1 ready + X0 reads done

    // ---- layer2: K=256, N=128; wave owns nt = w; X2 write @0 (X0 dead) ----
    f32x4 acc2[4];
    #pragma unroll
    for (int mt = 0; mt < 4; ++mt) acc2[mt] = (f32x4){bias2v, bias2v, bias2v, bias2v};
    {
        const ushort_t* bp = bt2 + (size_t)(h*64 + w)*512 + (size_t)l*8;
        half8 b2b[2];
        b2b[0] = *(const half8*)(bp);
        #pragma unroll
        for (int ks = 0; ks < 8; ++ks) {
            if (ks < 7) b2b[(ks+1)&1] = *(const half8*)(bp + (size_t)(ks+1)*4096);
            __builtin_amdgcn_s_setprio(1);
            #pragma unroll
            for (int mt = 0; mt < 4; ++mt) {
                const half8 a0 = *(const half8*)(X1n + (((mt*16 + lrow)*512 + ks*64 + lko*16) ^ ((lrow & 7) << 4)));
                acc2[mt] = __builtin_amdgcn_mfma_f32_16x16x32_f16(a0, b2b[ks&1], acc2[mt], 0, 0, 0);
            }
            __builtin_amdgcn_s_setprio(0);
        }
    }
    {
        const int col = w*16 + lrow;
        #pragma unroll
        for (int mt = 0; mt < 4; ++mt)
            #pragma unroll
            for (int r = 0; r < 4; ++r) {
                const int row = mt*16 + lko*4 + r;
                *(ushort_t*)(X2 + ((row*256 + col*2) ^ ((row & 7) << 4))) =
                    f2h_s(fmaxf(acc2[mt][r], 0.f));
            }
    }
    __syncthreads();                                           // [bar 3] X2 ready

    // ---- layer3: K=128, N=64; wave = (nt=w&3, mhalf=w>>2); X3h @16384 (disjoint) ----
    const int mhalf = w >> 2;
    f32x4 acc3[2];
    acc3[0] = (f32x4){bias3v, bias3v, bias3v, bias3v};
    acc3[1] = (f32x4){bias3v, bias3v, bias3v, bias3v};
    {
        const ushort_t* bp = bt3 + (size_t)(h*16 + (w & 3))*512 + (size_t)l*8;
        #pragma unroll
        for (int ks = 0; ks < 4; ++ks) {
            const half8 bf = *(const half8*)(bp + (size_t)ks*2048);
            __builtin_amdgcn_s_setprio(1);
            #pragma unroll
            for (int mi = 0; mi < 2; ++mi) {
                const int mt = mhalf*2 + mi;
                const half8 a0 = *(const half8*)(X2 + (((mt*16 + lrow)*256 + ks*64 + lko*16) ^ ((lrow & 7) << 4)));
                acc3[mi] = __builtin_amdgcn_mfma_f32_16x16x32_f16(a0, bf, acc3[mi], 0, 0, 0);
            }
            __builtin_amdgcn_s_setprio(0);
        }
    }
    {
        const int col = (w & 3)*16 + lrow;
        #pragma unroll
        for (int mi = 0; mi < 2; ++mi) {
            const int mt = mhalf*2 + mi;
            #pragma unroll
            for (int r = 0; r < 4; ++r) {
                const int row = mt*16 + lko*4 + r;
                *(ushort_t*)(X3h + ((row*128 + col*2) ^ ((row & 7) << 4))) =
                    f2h_s(fmaxf(acc3[mi][r], 0.f));
            }
        }
    }
    __syncthreads();                                           // [bar 4] X3 ready

    // ---- layer4 via MFMA: M=64, K=64, N=16 (cols 0..3 real); waves 0..3, direct output ----
    if (w < 4) {
        const int mt = w;
        f32x4 acc4 = (f32x4){bias4v, bias4v, bias4v, bias4v};
        const ushort_t* bp = bt4 + (size_t)(h*2)*512 + (size_t)l*8;
        #pragma unroll
        for (int ks = 0; ks < 2; ++ks) {
            const half8 bf = *(const half8*)(bp + (size_t)ks*512);
            const half8 a0 = *(const half8*)(X3h + (((mt*16 + lrow)*128 + ks*64 + lko*16) ^ ((lrow & 7) << 4)));
            acc4 = __builtin_amdgcn_mfma_f32_16x16x32_f16(a0, bf, acc4, 0, 0, 0);
        }

        if (isH3) {
            if (lrow == 0) {
                #pragma unroll
                for (int r = 0; r < 4; ++r) {
                    const int row = mt*16 + lko*4 + r;
                    out[O_PLANE + b*1024 + (t0 + (row >> 5))*32 + (row & 31)] =
                        1.f / (1.f + expf(-acc4[r]));
                }
            }
        } else {
            const int nj = (h == 0) ? 1 : ((h == 1) ? 4 : 3);
            float v = 0.f;
            #pragma unroll
            for (int r = 0; r < 4; ++r) {
                const int row = mt*16 + lko*4 + r;
                const int tq = row >> 4, sr = row & 15;
                if ((t0 + tq) < n0 && sr < n1) v += acc4[r];
            }
            v += __shfl_down(v, 32);
            v += __shfl_down(v, 16);
            if (lko == 0 && lrow < nj) {
                const int slot = (h == 0) ? 0 : ((h == 1) ? 1 + lrow : 5 + lrow);
                atomicAdd(&accbuf[b*8 + slot], v);
            }
        }
    }
}

// ================= K-final: finalize scalar reductions =================
__global__ __launch_bounds__(512) void k_final(
    const int* __restrict__ np_, const float* __restrict__ acc, float* __restrict__ out)
{
    const int tid = threadIdx.x;
    const int b = tid >> 3, sl = tid & 7;
    const int n0 = np_[2*b], n1 = np_[2*b+1];
    const float pf = (float)(n0 * n1);
    const float v = acc[b*8 + sl] / pf;
    if (sl == 0)      out[O_CAM + b] = 1.f / (1.f + expf(-v));
    else if (sl <= 4) out[O_ROT + b*4 + (sl - 1)] = v;
    else              out[O_TRANS + b*3 + (sl - 5)] = v;
}

extern "C" void kernel_launch(void* const* d_in, const int* in_sizes, int n_in,
                              void* d_out, int out_size, void* d_ws, size_t ws_size,
                              hipStream_t stream) {
    (void)in_sizes; (void)n_in; (void)out_size; (void)ws_size;
    const float* emb = (const float*)d_in[0];
    const int*   np_ = (const int*)d_in[1];
    const float* w0  = (const float*)d_in[2];
    const float* b0  = (const float*)d_in[3];
    const float* w1  = (const float*)d_in[4];
    const float* b1  = (const float*)d_in[5];
    const float* w2  = (const float*)d_in[6];
    const float* b2  = (const float*)d_in[7];
    const float* w3  = (const float*)d_in[8];
    const float* b3  = (const float*)d_in[9];
    const float* w4  = (const float*)d_in[10];
    const float* b4  = (const float*)d_in[11];

    char* W = (char*)d_ws;
    float* out = (float*)d_out;
    float*    g1   = (float*)(W + B_G1);
    float*    g2   = (float*)(W + B_G2);
    float*    acc  = (float*)(W + B_ACC);
    ushort_t* Abf  = (ushort_t*)(W + B_ABF);
    ushort_t* Cbf  = (ushort_t*)(W + B_CBF);
    ushort_t* bt1  = (ushort_t*)(W + B_BT1);
    ushort_t* bt2  = (ushort_t*)(W + B_BT2);
    ushort_t* bt3  = (ushort_t*)(W + B_BT3);
    ushort_t* bt0f = (ushort_t*)(W + B_BT0F);
    ushort_t* bt4  = (ushort_t*)(W + B_BT4);

    k_prep<<<1395, 256, 0, stream>>>(emb, np_, w0, w1, w2, w3, w4,
                                     bt0f, bt1, bt2, bt3, bt4, g1, g2, acc, out);
    k_AC<<<512, 256, 0, stream>>>(emb, bt0f, g1, g2, b0, Abf, Cbf);
    k_mlp<<<1792, 512, 0, stream>>>(Abf, Cbf, bt1, bt2, bt3, bt4,
                                    b1, b2, b3, b4, np_, out, acc);
    k_final<<<1, 512, 0, stream>>>(np_, acc, out);
}